// Round 6
// baseline (896.821 us; speedup 1.0000x reference)
//
#include <hip/hip_runtime.h>
#include <hip/hip_fp16.h>
#include <math.h>

#define N_NODES  50000
#define N_EDGES  800000
#define E_TOT    850000        // N_EDGES + N_NODES self loops
#define N_GRAPHS 128
#define F_IN     36
#define NH1      10
#define C1       36
#define D1       360           // NH1*C1
#define D2       128
#define XW       18            // u32 words per x row (36 halves)

#define SCHUNK  512
#define NCHUNK  98             // ceil(50000/512)

typedef unsigned int u32;

#if defined(__has_builtin)
#if __has_builtin(__builtin_amdgcn_fdot2)
#define HAVE_FDOT2 1
#endif
#endif
#ifndef HAVE_FDOT2
#define HAVE_FDOT2 0
#endif

typedef _Float16 h2v __attribute__((ext_vector_type(2)));

static __device__ __forceinline__ float2 h2f(u32 u) {
  __half2 h = __builtin_bit_cast(__half2, u);
  return __half22float2(h);
}
static __device__ __forceinline__ u32 f2h2(float a, float b) {
  __half2 h = __floats2half2_rn(a, b);
  return __builtin_bit_cast(u32, h);
}
static __device__ __forceinline__ float dot2acc(u32 a, u32 b, float acc) {
#if HAVE_FDOT2
  return __builtin_amdgcn_fdot2(__builtin_bit_cast(h2v, a), __builtin_bit_cast(h2v, b), acc, false);
#else
  float2 fa = h2f(a), fb = h2f(b);
  return fmaf(fa.x, fb.x, fmaf(fa.y, fb.y, acc));
#endif
}

// ---------------- init ----------------
__global__ void k_init(int* counts, u32* pool) {
  int i = blockIdx.x * blockDim.x + threadIdx.x;
  if (i < N_NODES) counts[i] = 0;
  if (i < N_GRAPHS * D2) pool[i] = 0u;
}

// ---------------- dst histogram ----------------
__global__ void k_hist(const int* ei, int* counts) {
  int e = blockIdx.x * blockDim.x + threadIdx.x;
  if (e >= E_TOT) return;
  int d = (e < N_EDGES) ? ei[N_EDGES + e] : (e - N_EDGES);
  atomicAdd(&counts[d], 1);
}

// ---------------- scan (3 kernels) ----------------
__global__ void k_scan1(const int* counts, int* partial) {
  __shared__ int red[256];
  int b = blockIdx.x, t = threadIdx.x;
  int base = b * SCHUNK;
  int v = 0;
  int i0 = base + t, i1 = base + t + 256;
  if (i0 < N_NODES) v += counts[i0];
  if (i1 < N_NODES) v += counts[i1];
  red[t] = v; __syncthreads();
  for (int off = 128; off; off >>= 1) {
    if (t < off) red[t] += red[t + off];
    __syncthreads();
  }
  if (t == 0) partial[b] = red[0];
}

__global__ void k_scan2(const int* partial, int* chunk_off, int* row_ptr) {
  if (threadIdx.x == 0 && blockIdx.x == 0) {
    int acc = 0;
    for (int i = 0; i < NCHUNK; i++) { chunk_off[i] = acc; acc += partial[i]; }
    row_ptr[N_NODES] = acc;
  }
}

__global__ void k_scan3(const int* counts, const int* chunk_off, int* row_ptr, int* nxt) {
  __shared__ int tmp[SCHUNK];
  int b = blockIdx.x, t = threadIdx.x;
  int i = b * SCHUNK + t;
  int v = (i < N_NODES) ? counts[i] : 0;
  tmp[t] = v; __syncthreads();
  for (int off = 1; off < SCHUNK; off <<= 1) {
    int x = (t >= off) ? tmp[t - off] : 0;
    __syncthreads();
    tmp[t] += x;
    __syncthreads();
  }
  if (i < N_NODES) {
    int excl = chunk_off[b] + tmp[t] - v;   // exclusive prefix
    row_ptr[i] = excl;
    nxt[i] = excl;
  }
}

// ---------------- scatter edges into CSR by dst ----------------
__global__ void k_scatter(const int* ei, int* nxt, int* csr_src) {
  int e = blockIdx.x * blockDim.x + threadIdx.x;
  if (e >= E_TOT) return;
  int s, d;
  if (e < N_EDGES) { s = ei[e]; d = ei[N_EDGES + e]; }
  else             { s = d = e - N_EDGES; }
  int pos = atomicAdd(&nxt[d], 1);
  csr_src[pos] = s;
}

// ---------------- merged weight prep: w_als/w_ald + W1t2 + W2h ----------------
// needs D1 + D1*18 + 180*128 = 29880 threads -> 117 blocks x 256
__global__ void k_prep(const float* __restrict__ W1, const float* __restrict__ asrc,
                       const float* __restrict__ adst, const float* __restrict__ W2,
                       float* w_als, float* w_ald, u32* W1t2, u32* W2h) {
  int id = blockIdx.x * blockDim.x + threadIdx.x;
  if (id < D1) {
    // w_als[h*36+k] = sum_c W1[k, h*36+c]*a_src[h,c]
    int h = id / F_IN, k = id - h * F_IN;
    float sa = 0.f, sd = 0.f;
    for (int c = 0; c < C1; c++) {
      float wv = W1[k * D1 + h * C1 + c];
      sa = fmaf(wv, asrc[h * C1 + c], sa);
      sd = fmaf(wv, adst[h * C1 + c], sd);
    }
    w_als[id] = sa; w_ald[id] = sd;
  } else if (id < D1 + D1 * (F_IN / 2)) {
    // W1 transposed + k-paired fp16: W1t2[hc][kp]
    int i = id - D1;
    int hc = i / (F_IN / 2), kp = i - hc * (F_IN / 2);
    W1t2[i] = f2h2(W1[(2 * kp) * D1 + hc], W1[(2 * kp + 1) * D1 + hc]);
  } else if (id < D1 + D1 * (F_IN / 2) + (D1 / 2) * D2) {
    // W2 k-paired fp16: W2h[kp][col]
    int i = id - D1 - D1 * (F_IN / 2);
    int kp = i / D2, col = i - kp * D2;
    W2h[i] = f2h2(W2[(2 * kp) * D2 + col], W2[(2 * kp + 1) * D2 + col]);
  }
}

// ---------------- layer-1 attention scalars + x fp16 pack ----------------
__global__ __launch_bounds__(256)
void k_als1(const float* __restrict__ x, const float* __restrict__ w_als,
            const float* __restrict__ w_ald, float* als, float* ald,
            u32* __restrict__ xh2) {
  __shared__ float xs[64][F_IN + 1];
  __shared__ float wa[D1], wd[D1];
  int t = threadIdx.x;
  int nb = blockIdx.x * 64;
  for (int i = t; i < D1; i += 256) { wa[i] = w_als[i]; wd[i] = w_ald[i]; }
  int lim = min(64, N_NODES - nb);
  for (int i = t; i < lim * F_IN; i += 256) {
    int n = i / F_IN, k = i - n * F_IN;
    xs[n][k] = x[(size_t)(nb + n) * F_IN + k];
  }
  __syncthreads();
  // pack x -> fp16 pairs
  for (int i = t; i < lim * XW; i += 256) {
    int n = i / XW, kp = i - n * XW;
    xh2[(size_t)(nb + n) * XW + kp] = f2h2(xs[n][2 * kp], xs[n][2 * kp + 1]);
  }
  for (int pair = t; pair < lim * NH1; pair += 256) {
    int n = pair / NH1, h = pair - n * NH1;
    const float* xp = xs[n];
    const float* wap = &wa[h * F_IN];
    const float* wdp = &wd[h * F_IN];
    float sa = 0.f, sd = 0.f;
#pragma unroll
    for (int k = 0; k < F_IN; k++) {
      float xv = xp[k];
      sa = fmaf(xv, wap[k], sa);
      sd = fmaf(xv, wdp[k], sd);
    }
    als[(size_t)(nb + n) * NH1 + h] = sa;
    ald[(size_t)(nb + n) * NH1 + h] = sd;
  }
}

// ---------------- layer-1 fused softmax + x-aggregation (per node, 1 wave) ----------------
// acc u32-slot s = h*18+kp (halves h*36+2kp, +1); lane owns s in {lane, lane+64, lane+128}
__global__ __launch_bounds__(256)
void k_agg1(const u32* __restrict__ xrow, const float* __restrict__ als,
            const float* __restrict__ ald, const int* __restrict__ row_ptr,
            const int* __restrict__ csr_src, u32* __restrict__ aggx2) {
  __shared__ float pl[4][64][NH1];
  int w = threadIdx.x >> 6, lane = threadIdx.x & 63;
  int node = blockIdx.x * 4 + w;     // 50000 = 4*12500 exact
  int beg = row_ptr[node], end = row_ptr[node + 1];

  int h0 = lane / XW,  kp0 = lane - XW * h0;
  int s1 = lane + 64;
  int h1i = s1 / XW,   kp1 = s1 - XW * h1i;
  bool v2 = lane < 52;               // slot lane+128 < 180
  int s2 = v2 ? lane + 128 : 179;
  int h2i = s2 / XW,   kp2 = s2 - XW * h2i;

  float aldn[NH1];
#pragma unroll
  for (int h = 0; h < NH1; h++) aldn[h] = ald[(size_t)node * NH1 + h];
  float a0x = 0.f, a0y = 0.f, a1x = 0.f, a1y = 0.f, a2x = 0.f, a2y = 0.f;
  float sp[NH1];
#pragma unroll
  for (int h = 0; h < NH1; h++) sp[h] = 0.f;

  for (int base = beg; base < end; base += 64) {
    int cnt = min(64, end - base);
    float p[NH1];
    int msrc = 0;
    if (lane < cnt) {
      msrc = csr_src[base + lane];
      const float2* ap = (const float2*)(als + (size_t)msrc * NH1);
#pragma unroll
      for (int q = 0; q < 5; q++) {
        float2 v = ap[q];
        float v0 = v.x + aldn[2 * q];
        float v1 = v.y + aldn[2 * q + 1];
        v0 = v0 > 0.f ? v0 : 0.2f * v0;     // leaky_relu
        v1 = v1 > 0.f ? v1 : 0.2f * v1;
        p[2 * q] = __expf(v0);              // no max-shift: logits O(1)
        p[2 * q + 1] = __expf(v1);
      }
    } else {
#pragma unroll
      for (int h = 0; h < NH1; h++) p[h] = 0.f;
    }
#pragma unroll
    for (int h = 0; h < NH1; h++) sp[h] += p[h];
    float2* plw = (float2*)pl[w][lane];
#pragma unroll
    for (int q = 0; q < 5; q++) plw[q] = float2{p[2 * q], p[2 * q + 1]};
    __builtin_amdgcn_wave_barrier();

    int j2 = 0;
    for (; j2 + 4 <= cnt; j2 += 4) {
      int sA = __shfl(msrc, j2),     sB = __shfl(msrc, j2 + 1);
      int sC = __shfl(msrc, j2 + 2), sD = __shfl(msrc, j2 + 3);
      const u32* ra = xrow + (size_t)sA * XW;
      const u32* rb = xrow + (size_t)sB * XW;
      const u32* rc = xrow + (size_t)sC * XW;
      const u32* rd = xrow + (size_t)sD * XW;
      u32 ua0 = ra[kp0], ua1 = ra[kp1], ua2 = ra[kp2];
      u32 ub0 = rb[kp0], ub1 = rb[kp1], ub2 = rb[kp2];
      u32 uc0 = rc[kp0], uc1 = rc[kp1], uc2 = rc[kp2];
      u32 ud0 = rd[kp0], ud1 = rd[kp1], ud2 = rd[kp2];
      const float* pA = pl[w][j2];
      const float* pB = pl[w][j2 + 1];
      const float* pC = pl[w][j2 + 2];
      const float* pD = pl[w][j2 + 3];
      float cA0 = pA[h0], cA1 = pA[h1i], cA2 = pA[h2i];
      float cB0 = pB[h0], cB1 = pB[h1i], cB2 = pB[h2i];
      float cC0 = pC[h0], cC1 = pC[h1i], cC2 = pC[h2i];
      float cD0 = pD[h0], cD1 = pD[h1i], cD2 = pD[h2i];
      float2 f;
      f = h2f(ua0); a0x = fmaf(cA0, f.x, a0x); a0y = fmaf(cA0, f.y, a0y);
      f = h2f(ua1); a1x = fmaf(cA1, f.x, a1x); a1y = fmaf(cA1, f.y, a1y);
      f = h2f(ua2); a2x = fmaf(cA2, f.x, a2x); a2y = fmaf(cA2, f.y, a2y);
      f = h2f(ub0); a0x = fmaf(cB0, f.x, a0x); a0y = fmaf(cB0, f.y, a0y);
      f = h2f(ub1); a1x = fmaf(cB1, f.x, a1x); a1y = fmaf(cB1, f.y, a1y);
      f = h2f(ub2); a2x = fmaf(cB2, f.x, a2x); a2y = fmaf(cB2, f.y, a2y);
      f = h2f(uc0); a0x = fmaf(cC0, f.x, a0x); a0y = fmaf(cC0, f.y, a0y);
      f = h2f(uc1); a1x = fmaf(cC1, f.x, a1x); a1y = fmaf(cC1, f.y, a1y);
      f = h2f(uc2); a2x = fmaf(cC2, f.x, a2x); a2y = fmaf(cC2, f.y, a2y);
      f = h2f(ud0); a0x = fmaf(cD0, f.x, a0x); a0y = fmaf(cD0, f.y, a0y);
      f = h2f(ud1); a1x = fmaf(cD1, f.x, a1x); a1y = fmaf(cD1, f.y, a1y);
      f = h2f(ud2); a2x = fmaf(cD2, f.x, a2x); a2y = fmaf(cD2, f.y, a2y);
    }
    for (; j2 < cnt; j2++) {
      int sA = __shfl(msrc, j2);
      const u32* ra = xrow + (size_t)sA * XW;
      u32 ua0 = ra[kp0], ua1 = ra[kp1], ua2 = ra[kp2];
      const float* pA = pl[w][j2];
      float cA0 = pA[h0], cA1 = pA[h1i], cA2 = pA[h2i];
      float2 f;
      f = h2f(ua0); a0x = fmaf(cA0, f.x, a0x); a0y = fmaf(cA0, f.y, a0y);
      f = h2f(ua1); a1x = fmaf(cA1, f.x, a1x); a1y = fmaf(cA1, f.y, a1y);
      f = h2f(ua2); a2x = fmaf(cA2, f.x, a2x); a2y = fmaf(cA2, f.y, a2y);
    }
    __builtin_amdgcn_wave_barrier();
  }

  // reduce per-lane partial sums -> softmax denominators
#pragma unroll
  for (int h = 0; h < NH1; h++) {
    float t = sp[h];
#pragma unroll
    for (int off = 32; off; off >>= 1) t += __shfl_xor(t, off);
    sp[h] = t;
  }
  float i0 = 1.f / (sp[h0] + 1e-16f);
  float i1 = 1.f / (sp[h1i] + 1e-16f);
  float i2 = 1.f / (sp[h2i] + 1e-16f);
  u32* orow = aggx2 + (size_t)node * (D1 / 2);
  orow[lane] = f2h2(a0x * i0, a0y * i0);
  orow[lane + 64] = f2h2(a1x * i1, a1y * i1);
  if (v2) orow[lane + 128] = f2h2(a2x * i2, a2y * i2);
}

// ---------------- mix1: hact[n,hc] = ELU( sum_k agg[n,h,k]*W1[k,hc] + b1[hc] ) ----------------
#define MIX_NPB 32
__global__ __launch_bounds__(384)
void k_mix1(const u32* __restrict__ aggx2, const u32* __restrict__ W1t2,
            const float* __restrict__ b1, __half* __restrict__ hact) {
  __shared__ u32 ag[MIX_NPB][D1 / 2 + 4];
  int t = threadIdx.x;
  int nb = blockIdx.x * MIX_NPB;
  int lim = min(MIX_NPB, N_NODES - nb);
  const u32* gsrc = aggx2 + (size_t)nb * (D1 / 2);
  for (int i = t; i < lim * (D1 / 2); i += 384) {
    int n = i / (D1 / 2), k = i - n * (D1 / 2);
    ag[n][k] = gsrc[i];
  }
  __syncthreads();
  if (t < D1) {
    int h = t / C1;
    u32 wreg[F_IN / 2];
#pragma unroll
    for (int kp = 0; kp < F_IN / 2; kp++) wreg[kp] = W1t2[t * (F_IN / 2) + kp];
    float bj = b1[t];
    for (int n = 0; n < lim; n++) {
      const u32* a = &ag[n][h * (F_IN / 2)];
      float acc2 = 0.f;
#pragma unroll
      for (int kp = 0; kp < F_IN / 2; kp++) acc2 = dot2acc(a[kp], wreg[kp], acc2);
      float val = acc2 + bj;
      val = val > 0.f ? val : __expf(val) - 1.f;   // ELU
      hact[(size_t)(nb + n) * D1 + t] = __float2half(val);
    }
  }
}

// ---------------- GEMM2: h2 = hact @ W2  [N,128] via dot2 ----------------
#define G2_NPB 16
__global__ __launch_bounds__(256)
void k_gemm2(const __half* __restrict__ hacth, const u32* __restrict__ W2h,
             __half* __restrict__ h2h) {
  __shared__ u32 hs2[D1 / 2][G2_NPB];   // k-pair-major, node minor
  int nb = blockIdx.x * G2_NPB;
  int t = threadIdx.x;  // 256
  for (int i = t; i < G2_NPB * (D1 / 2); i += 256) {
    int n = i / (D1 / 2), kp = i - n * (D1 / 2);
    hs2[kp][n] = ((const u32*)(hacth + (size_t)(nb + n) * D1))[kp];
  }
  __syncthreads();
  int col = t & 127, ng = t >> 7;
  float acc[8];
#pragma unroll
  for (int i = 0; i < 8; i++) acc[i] = 0.f;
#pragma unroll 2
  for (int kp = 0; kp < D1 / 2; kp++) {
    u32 wv = W2h[kp * D2 + col];
    uint4 r0 = *(const uint4*)&hs2[kp][ng * 8];
    uint4 r1 = *(const uint4*)&hs2[kp][ng * 8 + 4];
    acc[0] = dot2acc(r0.x, wv, acc[0]);
    acc[1] = dot2acc(r0.y, wv, acc[1]);
    acc[2] = dot2acc(r0.z, wv, acc[2]);
    acc[3] = dot2acc(r0.w, wv, acc[3]);
    acc[4] = dot2acc(r1.x, wv, acc[4]);
    acc[5] = dot2acc(r1.y, wv, acc[5]);
    acc[6] = dot2acc(r1.z, wv, acc[6]);
    acc[7] = dot2acc(r1.w, wv, acc[7]);
  }
#pragma unroll
  for (int i = 0; i < 8; i++)
    h2h[(size_t)(nb + ng * 8 + i) * D2 + col] = __float2half(acc[i]);
}

// ---------------- attention scalars, layer 2 ----------------
__global__ void k_als2(const __half* __restrict__ h2h, const float* __restrict__ asrc,
                       const float* __restrict__ adst, float* als, float* ald) {
  int node = blockIdx.x * 4 + (threadIdx.x >> 6);
  int lane = threadIdx.x & 63;
  const u32* hr = (const u32*)(h2h + (size_t)node * D2);
  float2 f = h2f(hr[lane]);
  float2 a = ((const float2*)asrc)[lane];
  float2 d = ((const float2*)adst)[lane];
  float ps = f.x * a.x + f.y * a.y;
  float pd = f.x * d.x + f.y * d.y;
#pragma unroll
  for (int off = 32; off; off >>= 1) { ps += __shfl_xor(ps, off); pd += __shfl_xor(pd, off); }
  if (lane == 0) { als[node] = ps; ald[node] = pd; }
}

// ---------------- layer-2 fused softmax + aggregate + ReLU + max-pool ----------------
// 4-edge-parallel: sub=lane>>4 picks edge of quad, cq=lane&15 picks uint4 col-block.
__global__ __launch_bounds__(256)
void k_agg2(const __half* __restrict__ h2h, const float* __restrict__ als,
            const float* __restrict__ ald, const int* __restrict__ row_ptr,
            const int* __restrict__ csr_src, const float* __restrict__ b2,
            const int* __restrict__ batch, u32* __restrict__ pool) {
  int w = threadIdx.x >> 6, lane = threadIdx.x & 63;
  int node = blockIdx.x * 4 + w;
  int beg = row_ptr[node], end = row_ptr[node + 1];
  float aldn = ald[node];
  int sub = lane >> 4;      // edge-of-quad 0..3
  int cq  = lane & 15;      // uint4 index within row (16 per 128-half row)
  float acc[8];
#pragma unroll
  for (int i = 0; i < 8; i++) acc[i] = 0.f;
  float ssum = 0.f;

  for (int base = beg; base < end; base += 64) {
    int cnt = min(64, end - base);
    int msrc = 0; float p = 0.f;
    if (lane < cnt) {
      msrc = csr_src[base + lane];
      float vv = als[msrc] + aldn;
      vv = vv > 0.f ? vv : 0.2f * vv;
      p = __expf(vv);
    }
    ssum += p;   // per-lane partial; reduced at end

    int j4 = 0;
    for (; j4 + 8 <= cnt; j4 += 8) {
      int eA = j4 + sub, eB = j4 + 4 + sub;           // both <= 63
      int sA = __shfl(msrc, eA), sB = __shfl(msrc, eB);
      float cA = __shfl(p, eA),  cB = __shfl(p, eB);
      uint4 va = ((const uint4*)(h2h + (size_t)sA * D2))[cq];
      uint4 vb = ((const uint4*)(h2h + (size_t)sB * D2))[cq];
      float2 f;
      f = h2f(va.x); acc[0] = fmaf(cA, f.x, acc[0]); acc[1] = fmaf(cA, f.y, acc[1]);
      f = h2f(va.y); acc[2] = fmaf(cA, f.x, acc[2]); acc[3] = fmaf(cA, f.y, acc[3]);
      f = h2f(va.z); acc[4] = fmaf(cA, f.x, acc[4]); acc[5] = fmaf(cA, f.y, acc[5]);
      f = h2f(va.w); acc[6] = fmaf(cA, f.x, acc[6]); acc[7] = fmaf(cA, f.y, acc[7]);
      f = h2f(vb.x); acc[0] = fmaf(cB, f.x, acc[0]); acc[1] = fmaf(cB, f.y, acc[1]);
      f = h2f(vb.y); acc[2] = fmaf(cB, f.x, acc[2]); acc[3] = fmaf(cB, f.y, acc[3]);
      f = h2f(vb.z); acc[4] = fmaf(cB, f.x, acc[4]); acc[5] = fmaf(cB, f.y, acc[5]);
      f = h2f(vb.w); acc[6] = fmaf(cB, f.x, acc[6]); acc[7] = fmaf(cB, f.y, acc[7]);
    }
    for (; j4 < cnt; j4 += 4) {
      int eA = j4 + sub;                               // <= 63; p=0 past cnt
      int sA = __shfl(msrc, eA);
      float cA = __shfl(p, eA);
      uint4 va = ((const uint4*)(h2h + (size_t)sA * D2))[cq];
      float2 f;
      f = h2f(va.x); acc[0] = fmaf(cA, f.x, acc[0]); acc[1] = fmaf(cA, f.y, acc[1]);
      f = h2f(va.y); acc[2] = fmaf(cA, f.x, acc[2]); acc[3] = fmaf(cA, f.y, acc[3]);
      f = h2f(va.z); acc[4] = fmaf(cA, f.x, acc[4]); acc[5] = fmaf(cA, f.y, acc[5]);
      f = h2f(va.w); acc[6] = fmaf(cA, f.x, acc[6]); acc[7] = fmaf(cA, f.y, acc[7]);
    }
  }

  // cross-sub reduction: lanes {l, l^16, l^32, l^48} share cq
#pragma unroll
  for (int j = 0; j < 8; j++) {
    acc[j] += __shfl_xor(acc[j], 16);
    acc[j] += __shfl_xor(acc[j], 32);
  }
  float t2 = ssum;
#pragma unroll
  for (int off = 32; off; off >>= 1) t2 += __shfl_xor(t2, off);

  if (sub == 0) {
    float inv = 1.f / (t2 + 1e-16f);
    int g = batch[node];
    int cbase = 8 * cq;
    u32* pbase = pool + (size_t)g * D2 + cbase;
#pragma unroll
    for (int j = 0; j < 8; j++) {
      float v = fmaxf(acc[j] * inv + b2[cbase + j], 0.f);
      u32 vb = __float_as_uint(v);
      // monotonic non-negative pool: stale read only causes a redundant atomic
      if (vb > pbase[j]) atomicMax(&pbase[j], vb);
    }
  }
}

// ---------------- final FC + relu ----------------
__global__ void k_final(const float* __restrict__ pool, const float* __restrict__ fcw,
                        const float* __restrict__ fcb, float* __restrict__ out) {
  __shared__ float ps[D2];
  int g = blockIdx.x, j = threadIdx.x;
  ps[j] = pool[g * D2 + j];
  __syncthreads();
  float acc = 0.f;
  for (int c = 0; c < D2; c++) acc = fmaf(ps[c], fcw[c * D2 + j], acc);
  acc += fcb[j];
  out[g * D2 + j] = acc > 0.f ? acc : 0.f;
}

extern "C" void kernel_launch(void* const* d_in, const int* in_sizes, int n_in,
                              void* d_out, int out_size, void* d_ws, size_t ws_size,
                              hipStream_t stream) {
  const float* x     = (const float*)d_in[0];
  const int*   ei    = (const int*)d_in[1];
  const int*   batch = (const int*)d_in[2];
  const float* W1    = (const float*)d_in[3];
  const float* asrc1 = (const float*)d_in[4];
  const float* adst1 = (const float*)d_in[5];
  const float* b1    = (const float*)d_in[6];
  const float* W2    = (const float*)d_in[7];
  const float* asrc2 = (const float*)d_in[8];
  const float* adst2 = (const float*)d_in[9];
  const float* b2    = (const float*)d_in[10];
  const float* fcw   = (const float*)d_in[11];
  const float* fcb   = (const float*)d_in[12];
  float* out = (float*)d_out;

  char* w = (char*)d_ws;
  size_t off = 0;
  auto alloc = [&](size_t bytes) -> char* {
    char* p = w + off;
    off = (off + bytes + 255) & ~(size_t)255;
    return p;
  };
  int* counts    = (int*)alloc((size_t)N_NODES * 4);
  int* row_ptr   = (int*)alloc((size_t)(N_NODES + 1) * 4);
  int* nxt       = (int*)alloc((size_t)N_NODES * 4);
  int* csr_src   = (int*)alloc((size_t)E_TOT * 4);
  int* partial   = (int*)alloc(NCHUNK * 4);
  int* chunk_off = (int*)alloc(NCHUNK * 4);
  float* als1    = (float*)alloc((size_t)N_NODES * NH1 * 4);
  float* ald1    = (float*)alloc((size_t)N_NODES * NH1 * 4);
  float* als2    = (float*)alloc((size_t)N_NODES * 4);
  float* ald2    = (float*)alloc((size_t)N_NODES * 4);
  u32*   pool    = (u32*)alloc((size_t)N_GRAPHS * D2 * 4);
  float* w_als   = (float*)alloc((size_t)D1 * 4);
  float* w_ald   = (float*)alloc((size_t)D1 * 4);
  u32*   W1t2    = (u32*)alloc((size_t)D1 * (F_IN / 2) * 4);
  u32*   W2h     = (u32*)alloc((size_t)(D1 / 2) * D2 * 4);
  u32*   xh2     = (u32*)alloc((size_t)N_NODES * XW * 4);
  u32*   aggx2   = (u32*)alloc((size_t)N_NODES * (D1 / 2) * 4);
  __half* hacth  = (__half*)alloc((size_t)N_NODES * D1 * 2);
  __half* h2h    = (__half*)alloc((size_t)N_NODES * D2 * 2);

  k_init<<<dim3(196), dim3(256), 0, stream>>>(counts, pool);
  k_hist<<<dim3((E_TOT + 255) / 256), dim3(256), 0, stream>>>(ei, counts);
  k_scan1<<<dim3(NCHUNK), dim3(256), 0, stream>>>(counts, partial);
  k_scan2<<<dim3(1), dim3(64), 0, stream>>>(partial, chunk_off, row_ptr);
  k_scan3<<<dim3(NCHUNK), dim3(SCHUNK), 0, stream>>>(counts, chunk_off, row_ptr, nxt);
  k_scatter<<<dim3((E_TOT + 255) / 256), dim3(256), 0, stream>>>(ei, nxt, csr_src);
  k_prep<<<dim3(117), dim3(256), 0, stream>>>(W1, asrc1, adst1, W2, w_als, w_ald, W1t2, W2h);

  k_als1<<<dim3((N_NODES + 63) / 64), dim3(256), 0, stream>>>(x, w_als, w_ald, als1, ald1, xh2);
  k_agg1<<<dim3(N_NODES / 4), dim3(256), 0, stream>>>(xh2, als1, ald1, row_ptr, csr_src, aggx2);
  k_mix1<<<dim3((N_NODES + MIX_NPB - 1) / MIX_NPB), dim3(384), 0, stream>>>(aggx2, W1t2, b1, hacth);

  k_gemm2<<<dim3(N_NODES / G2_NPB), dim3(256), 0, stream>>>(hacth, W2h, h2h);
  k_als2<<<dim3(N_NODES / 4), dim3(256), 0, stream>>>(h2h, asrc2, adst2, als2, ald2);
  k_agg2<<<dim3(N_NODES / 4), dim3(256), 0, stream>>>(h2h, als2, ald2, row_ptr, csr_src,
                                                      b2, batch, pool);

  k_final<<<dim3(N_GRAPHS), dim3(D2), 0, stream>>>((const float*)pool, fcw, fcb, out);

  (void)in_sizes; (void)n_in; (void)out_size; (void)ws_size;
}

// Round 12
// 551.862 us; speedup vs baseline: 1.6251x; 1.6251x over previous
//
#include <hip/hip_runtime.h>
#include <hip/hip_fp16.h>
#include <math.h>

#define N_NODES  50000
#define N_EDGES  800000
#define E_TOT    850000        // N_EDGES + N_NODES self loops
#define N_GRAPHS 128
#define F_IN     36
#define NH1      10
#define C1       36
#define D1       360           // NH1*C1
#define D2       128
#define XW       18            // u32 words per x row (36 halves)
#define HPAD     384           // hact padded K (halves)
#define KW       192           // u32 words per hact row
#define KCH      24            // k-chunks of 16
#define W2FW     24576         // u32 words in W2f fragment pack (8t*24kc*64l*4h /2)

#define SCHUNK  512
#define NCHUNK  98             // ceil(50000/512)

typedef unsigned int u32;

#if defined(__has_builtin)
#if __has_builtin(__builtin_amdgcn_fdot2)
#define HAVE_FDOT2 1
#endif
#endif
#ifndef HAVE_FDOT2
#define HAVE_FDOT2 0
#endif

typedef _Float16 h2v __attribute__((ext_vector_type(2)));
typedef _Float16 f16x4 __attribute__((ext_vector_type(4)));
typedef float f32x4 __attribute__((ext_vector_type(4)));

static __device__ __forceinline__ float2 h2f(u32 u) {
  __half2 h = __builtin_bit_cast(__half2, u);
  return __half22float2(h);
}
static __device__ __forceinline__ u32 f2h2(float a, float b) {
  __half2 h = __floats2half2_rn(a, b);
  return __builtin_bit_cast(u32, h);
}
static __device__ __forceinline__ float dot2acc(u32 a, u32 b, float acc) {
#if HAVE_FDOT2
  return __builtin_amdgcn_fdot2(__builtin_bit_cast(h2v, a), __builtin_bit_cast(h2v, b), acc, false);
#else
  float2 fa = h2f(a), fb = h2f(b);
  return fmaf(fa.x, fb.x, fmaf(fa.y, fb.y, acc));
#endif
}

// ---------------- init ----------------
__global__ void k_init(int* counts, u32* pool) {
  int i = blockIdx.x * blockDim.x + threadIdx.x;
  if (i < N_NODES) counts[i] = 0;
  if (i < N_GRAPHS * D2) pool[i] = 0u;
}

// ---------------- dst histogram ----------------
__global__ void k_hist(const int* ei, int* counts) {
  int e = blockIdx.x * blockDim.x + threadIdx.x;
  if (e >= E_TOT) return;
  int d = (e < N_EDGES) ? ei[N_EDGES + e] : (e - N_EDGES);
  atomicAdd(&counts[d], 1);
}

// ---------------- scan (3 kernels) ----------------
__global__ void k_scan1(const int* counts, int* partial) {
  __shared__ int red[256];
  int b = blockIdx.x, t = threadIdx.x;
  int base = b * SCHUNK;
  int v = 0;
  int i0 = base + t, i1 = base + t + 256;
  if (i0 < N_NODES) v += counts[i0];
  if (i1 < N_NODES) v += counts[i1];
  red[t] = v; __syncthreads();
  for (int off = 128; off; off >>= 1) {
    if (t < off) red[t] += red[t + off];
    __syncthreads();
  }
  if (t == 0) partial[b] = red[0];
}

__global__ void k_scan2(const int* partial, int* chunk_off, int* row_ptr) {
  if (threadIdx.x == 0 && blockIdx.x == 0) {
    int acc = 0;
    for (int i = 0; i < NCHUNK; i++) { chunk_off[i] = acc; acc += partial[i]; }
    row_ptr[N_NODES] = acc;
  }
}

__global__ void k_scan3(const int* counts, const int* chunk_off, int* row_ptr, int* nxt) {
  __shared__ int tmp[SCHUNK];
  int b = blockIdx.x, t = threadIdx.x;
  int i = b * SCHUNK + t;
  int v = (i < N_NODES) ? counts[i] : 0;
  tmp[t] = v; __syncthreads();
  for (int off = 1; off < SCHUNK; off <<= 1) {
    int x = (t >= off) ? tmp[t - off] : 0;
    __syncthreads();
    tmp[t] += x;
    __syncthreads();
  }
  if (i < N_NODES) {
    int excl = chunk_off[b] + tmp[t] - v;   // exclusive prefix
    row_ptr[i] = excl;
    nxt[i] = excl;
  }
}

// ---------------- scatter edges into CSR by dst ----------------
__global__ void k_scatter(const int* ei, int* nxt, int* csr_src) {
  int e = blockIdx.x * blockDim.x + threadIdx.x;
  if (e >= E_TOT) return;
  int s, d;
  if (e < N_EDGES) { s = ei[e]; d = ei[N_EDGES + e]; }
  else             { s = d = e - N_EDGES; }
  int pos = atomicAdd(&nxt[d], 1);
  csr_src[pos] = s;
}

// ---------------- merged weight prep: w_als/w_ald + W1t2 + W2f ----------------
// ids: D1 (360) + D1*18 (6480) + W2FW (24576) = 31416 -> 123 blocks x 256
__global__ void k_prep(const float* __restrict__ W1, const float* __restrict__ asrc,
                       const float* __restrict__ adst, const float* __restrict__ W2,
                       float* w_als, float* w_ald, u32* W1t2, u32* W2f) {
  int id = blockIdx.x * blockDim.x + threadIdx.x;
  if (id < D1) {
    // w_als[h*36+k] = sum_c W1[k, h*36+c]*a_src[h,c]
    int h = id / F_IN, k = id - h * F_IN;
    float sa = 0.f, sd = 0.f;
    for (int c = 0; c < C1; c++) {
      float wv = W1[k * D1 + h * C1 + c];
      sa = fmaf(wv, asrc[h * C1 + c], sa);
      sd = fmaf(wv, adst[h * C1 + c], sd);
    }
    w_als[id] = sa; w_ald[id] = sd;
  } else if (id < D1 + D1 * (F_IN / 2)) {
    // W1 transposed + k-paired fp16: W1t2[hc][kp]
    int i = id - D1;
    int hc = i / (F_IN / 2), kp = i - hc * (F_IN / 2);
    W1t2[i] = f2h2(W1[(2 * kp) * D1 + hc], W1[(2 * kp + 1) * D1 + hc]);
  } else if (id < D1 + D1 * (F_IN / 2) + W2FW) {
    // W2 in exact mfma_16x16x16f16 B-fragment order:
    // uint2 index (kc*8+t)*64+lane holds B[k = kc*16+4*(lane>>4)+j][col = 16t+(lane&15)], j=0..3
    int i = id - D1 - D1 * (F_IN / 2);
    int q    = i & 1;           // half-pair within lane's 4 halves
    int lane = (i >> 1) & 63;
    int rem  = i >> 7;
    int t    = rem & 7;
    int kc   = rem >> 3;        // 0..23
    int k0   = kc * 16 + ((lane >> 4) << 2) + 2 * q;
    int col  = t * 16 + (lane & 15);
    float w0 = (k0     < D1) ? W2[(size_t)k0 * D2 + col]       : 0.f;
    float w1 = (k0 + 1 < D1) ? W2[(size_t)(k0 + 1) * D2 + col] : 0.f;
    W2f[i] = f2h2(w0, w1);
  }
}

// ---------------- layer-1 attention scalars + x fp16 pack ----------------
__global__ __launch_bounds__(256)
void k_als1(const float* __restrict__ x, const float* __restrict__ w_als,
            const float* __restrict__ w_ald, float* als, float* ald,
            u32* __restrict__ xh2) {
  __shared__ float xs[64][F_IN + 1];
  __shared__ float wa[D1], wd[D1];
  int t = threadIdx.x;
  int nb = blockIdx.x * 64;
  for (int i = t; i < D1; i += 256) { wa[i] = w_als[i]; wd[i] = w_ald[i]; }
  int lim = min(64, N_NODES - nb);
  for (int i = t; i < lim * F_IN; i += 256) {
    int n = i / F_IN, k = i - n * F_IN;
    xs[n][k] = x[(size_t)(nb + n) * F_IN + k];
  }
  __syncthreads();
  // pack x -> fp16 pairs
  for (int i = t; i < lim * XW; i += 256) {
    int n = i / XW, kp = i - n * XW;
    xh2[(size_t)(nb + n) * XW + kp] = f2h2(xs[n][2 * kp], xs[n][2 * kp + 1]);
  }
  for (int pair = t; pair < lim * NH1; pair += 256) {
    int n = pair / NH1, h = pair - n * NH1;
    const float* xp = xs[n];
    const float* wap = &wa[h * F_IN];
    const float* wdp = &wd[h * F_IN];
    float sa = 0.f, sd = 0.f;
#pragma unroll
    for (int k = 0; k < F_IN; k++) {
      float xv = xp[k];
      sa = fmaf(xv, wap[k], sa);
      sd = fmaf(xv, wdp[k], sd);
    }
    als[(size_t)(nb + n) * NH1 + h] = sa;
    ald[(size_t)(nb + n) * NH1 + h] = sd;
  }
}

// ---------------- layer-1 fused softmax + x-aggregation (per node, 1 wave) ----------------
// acc u32-slot s = h*18+kp (halves h*36+2kp, +1); lane owns s in {lane, lane+64, lane+128}
__global__ __launch_bounds__(256)
void k_agg1(const u32* __restrict__ xrow, const float* __restrict__ als,
            const float* __restrict__ ald, const int* __restrict__ row_ptr,
            const int* __restrict__ csr_src, u32* __restrict__ aggx2) {
  __shared__ float pl[4][64][NH1];
  int w = threadIdx.x >> 6, lane = threadIdx.x & 63;
  int node = blockIdx.x * 4 + w;     // 50000 = 4*12500 exact
  int beg = row_ptr[node], end = row_ptr[node + 1];

  int h0 = lane / XW,  kp0 = lane - XW * h0;
  int s1 = lane + 64;
  int h1i = s1 / XW,   kp1 = s1 - XW * h1i;
  bool v2 = lane < 52;               // slot lane+128 < 180
  int s2 = v2 ? lane + 128 : 179;
  int h2i = s2 / XW,   kp2 = s2 - XW * h2i;

  float aldn[NH1];
#pragma unroll
  for (int h = 0; h < NH1; h++) aldn[h] = ald[(size_t)node * NH1 + h];
  float a0x = 0.f, a0y = 0.f, a1x = 0.f, a1y = 0.f, a2x = 0.f, a2y = 0.f;
  float sp[NH1];
#pragma unroll
  for (int h = 0; h < NH1; h++) sp[h] = 0.f;

  for (int base = beg; base < end; base += 64) {
    int cnt = min(64, end - base);
    float p[NH1];
    int msrc = 0;
    if (lane < cnt) {
      msrc = csr_src[base + lane];
      const float2* ap = (const float2*)(als + (size_t)msrc * NH1);
#pragma unroll
      for (int q = 0; q < 5; q++) {
        float2 v = ap[q];
        float v0 = v.x + aldn[2 * q];
        float v1 = v.y + aldn[2 * q + 1];
        v0 = v0 > 0.f ? v0 : 0.2f * v0;     // leaky_relu
        v1 = v1 > 0.f ? v1 : 0.2f * v1;
        p[2 * q] = __expf(v0);              // no max-shift: logits O(1)
        p[2 * q + 1] = __expf(v1);
      }
    } else {
#pragma unroll
      for (int h = 0; h < NH1; h++) p[h] = 0.f;
    }
#pragma unroll
    for (int h = 0; h < NH1; h++) sp[h] += p[h];
    float2* plw = (float2*)pl[w][lane];
#pragma unroll
    for (int q = 0; q < 5; q++) plw[q] = float2{p[2 * q], p[2 * q + 1]};
    __builtin_amdgcn_wave_barrier();

    int j2 = 0;
    for (; j2 + 4 <= cnt; j2 += 4) {
      int sA = __shfl(msrc, j2),     sB = __shfl(msrc, j2 + 1);
      int sC = __shfl(msrc, j2 + 2), sD = __shfl(msrc, j2 + 3);
      const u32* ra = xrow + (size_t)sA * XW;
      const u32* rb = xrow + (size_t)sB * XW;
      const u32* rc = xrow + (size_t)sC * XW;
      const u32* rd = xrow + (size_t)sD * XW;
      u32 ua0 = ra[kp0], ua1 = ra[kp1], ua2 = ra[kp2];
      u32 ub0 = rb[kp0], ub1 = rb[kp1], ub2 = rb[kp2];
      u32 uc0 = rc[kp0], uc1 = rc[kp1], uc2 = rc[kp2];
      u32 ud0 = rd[kp0], ud1 = rd[kp1], ud2 = rd[kp2];
      const float* pA = pl[w][j2];
      const float* pB = pl[w][j2 + 1];
      const float* pC = pl[w][j2 + 2];
      const float* pD = pl[w][j2 + 3];
      float cA0 = pA[h0], cA1 = pA[h1i], cA2 = pA[h2i];
      float cB0 = pB[h0], cB1 = pB[h1i], cB2 = pB[h2i];
      float cC0 = pC[h0], cC1 = pC[h1i], cC2 = pC[h2i];
      float cD0 = pD[h0], cD1 = pD[h1i], cD2 = pD[h2i];
      float2 f;
      f = h2f(ua0); a0x = fmaf(cA0, f.x, a0x); a0y = fmaf(cA0, f.y, a0y);
      f = h2f(ua1); a1x = fmaf(cA1, f.x, a1x); a1y = fmaf(cA1, f.y, a1y);
      f = h2f(ua2); a2x = fmaf(cA2, f.x, a2x); a2y = fmaf(cA2, f.y, a2y);
      f = h2f(ub0); a0x = fmaf(cB0, f.x, a0x); a0y = fmaf(cB0, f.y, a0y);
      f = h2f(ub1); a1x = fmaf(cB1, f.x, a1x); a1y = fmaf(cB1, f.y, a1y);
      f = h2f(ub2); a2x = fmaf(cB2, f.x, a2x); a2y = fmaf(cB2, f.y, a2y);
      f = h2f(uc0); a0x = fmaf(cC0, f.x, a0x); a0y = fmaf(cC0, f.y, a0y);
      f = h2f(uc1); a1x = fmaf(cC1, f.x, a1x); a1y = fmaf(cC1, f.y, a1y);
      f = h2f(uc2); a2x = fmaf(cC2, f.x, a2x); a2y = fmaf(cC2, f.y, a2y);
      f = h2f(ud0); a0x = fmaf(cD0, f.x, a0x); a0y = fmaf(cD0, f.y, a0y);
      f = h2f(ud1); a1x = fmaf(cD1, f.x, a1x); a1y = fmaf(cD1, f.y, a1y);
      f = h2f(ud2); a2x = fmaf(cD2, f.x, a2x); a2y = fmaf(cD2, f.y, a2y);
    }
    for (; j2 < cnt; j2++) {
      int sA = __shfl(msrc, j2);
      const u32* ra = xrow + (size_t)sA * XW;
      u32 ua0 = ra[kp0], ua1 = ra[kp1], ua2 = ra[kp2];
      const float* pA = pl[w][j2];
      float cA0 = pA[h0], cA1 = pA[h1i], cA2 = pA[h2i];
      float2 f;
      f = h2f(ua0); a0x = fmaf(cA0, f.x, a0x); a0y = fmaf(cA0, f.y, a0y);
      f = h2f(ua1); a1x = fmaf(cA1, f.x, a1x); a1y = fmaf(cA1, f.y, a1y);
      f = h2f(ua2); a2x = fmaf(cA2, f.x, a2x); a2y = fmaf(cA2, f.y, a2y);
    }
    __builtin_amdgcn_wave_barrier();
  }

  // reduce per-lane partial sums -> softmax denominators
#pragma unroll
  for (int h = 0; h < NH1; h++) {
    float t = sp[h];
#pragma unroll
    for (int off = 32; off; off >>= 1) t += __shfl_xor(t, off);
    sp[h] = t;
  }
  float i0 = 1.f / (sp[h0] + 1e-16f);
  float i1 = 1.f / (sp[h1i] + 1e-16f);
  float i2 = 1.f / (sp[h2i] + 1e-16f);
  u32* orow = aggx2 + (size_t)node * (D1 / 2);
  orow[lane] = f2h2(a0x * i0, a0y * i0);
  orow[lane + 64] = f2h2(a1x * i1, a1y * i1);
  if (v2) orow[lane + 128] = f2h2(a2x * i2, a2y * i2);
}

// ---------------- mix1: hact[n,hc] = ELU( sum_k agg[n,h,k]*W1[k,hc] + b1[hc] ), K-padded to 384 ----------------
#define MIX_NPB 32
__global__ __launch_bounds__(384)
void k_mix1(const u32* __restrict__ aggx2, const u32* __restrict__ W1t2,
            const float* __restrict__ b1, __half* __restrict__ hact) {
  __shared__ u32 ag[MIX_NPB][D1 / 2 + 4];
  int t = threadIdx.x;
  int nb = blockIdx.x * MIX_NPB;
  int lim = min(MIX_NPB, N_NODES - nb);
  const u32* gsrc = aggx2 + (size_t)nb * (D1 / 2);
  for (int i = t; i < lim * (D1 / 2); i += 384) {
    int n = i / (D1 / 2), k = i - n * (D1 / 2);
    ag[n][k] = gsrc[i];
  }
  __syncthreads();
  if (t < D1) {
    int h = t / C1;
    u32 wreg[F_IN / 2];
#pragma unroll
    for (int kp = 0; kp < F_IN / 2; kp++) wreg[kp] = W1t2[t * (F_IN / 2) + kp];
    float bj = b1[t];
    for (int n = 0; n < lim; n++) {
      const u32* a = &ag[n][h * (F_IN / 2)];
      float acc2 = 0.f;
#pragma unroll
      for (int kp = 0; kp < F_IN / 2; kp++) acc2 = dot2acc(a[kp], wreg[kp], acc2);
      float val = acc2 + bj;
      val = val > 0.f ? val : __expf(val) - 1.f;   // ELU
      hact[(size_t)(nb + n) * HPAD + t] = __float2half(val);
    }
  } else {
    // zero-fill K padding [360,384)
    for (int n = 0; n < lim; n++)
      hact[(size_t)(nb + n) * HPAD + t] = __float2half(0.f);
  }
}

// ---------------- GEMM2 via MFMA: h2 = hact @ W2  [N,128] ----------------
// v_mfma_f32_16x16x16f16: A lane l holds A[l&15][4*(l>>4)+j]; D: col=lane&15, row=4*(lane>>4)+r.
// Block = 4 waves x 16 rows = 64 rows; each wave does all 8 col-tiles over 24 k-chunks.
__global__ __launch_bounds__(256)
void k_gemm2(const u32* __restrict__ hact32, const u32* __restrict__ W2f,
             __half* __restrict__ h2h) {
  int w = threadIdx.x >> 6, l = threadIdx.x & 63;
  int rowbase = blockIdx.x * 64 + w * 16;
  int m = l & 15, kb = l >> 4;
  int arow = rowbase + m;
  if (arow >= N_NODES) arow = N_NODES - 1;     // clamp loads; stores guarded
  const u32* ap = hact32 + (size_t)arow * KW + kb * 2;
  const uint2* bp = (const uint2*)W2f;
  f32x4 acc[8];
#pragma unroll
  for (int t = 0; t < 8; t++) acc[t] = (f32x4){0.f, 0.f, 0.f, 0.f};
#pragma unroll 4
  for (int kc = 0; kc < KCH; kc++) {
    uint2 aw = *(const uint2*)(ap + kc * 8);
    f16x4 af = __builtin_bit_cast(f16x4, aw);
#pragma unroll
    for (int t = 0; t < 8; t++) {
      uint2 bw = bp[(kc * 8 + t) * 64 + l];
      acc[t] = __builtin_amdgcn_mfma_f32_16x16x16f16(af, __builtin_bit_cast(f16x4, bw),
                                                     acc[t], 0, 0, 0);
    }
  }
  int orow0 = rowbase + (l >> 4) * 4;
  int col0 = l & 15;
#pragma unroll
  for (int t = 0; t < 8; t++) {
#pragma unroll
    for (int r = 0; r < 4; r++) {
      int row = orow0 + r;
      if (row < N_NODES)
        h2h[(size_t)row * D2 + t * 16 + col0] = __float2half(acc[t][r]);
    }
  }
}

// ---------------- attention scalars, layer 2 ----------------
__global__ void k_als2(const __half* __restrict__ h2h, const float* __restrict__ asrc,
                       const float* __restrict__ adst, float* als, float* ald) {
  int node = blockIdx.x * 4 + (threadIdx.x >> 6);
  int lane = threadIdx.x & 63;
  const u32* hr = (const u32*)(h2h + (size_t)node * D2);
  float2 f = h2f(hr[lane]);
  float2 a = ((const float2*)asrc)[lane];
  float2 d = ((const float2*)adst)[lane];
  float ps = f.x * a.x + f.y * a.y;
  float pd = f.x * d.x + f.y * d.y;
#pragma unroll
  for (int off = 32; off; off >>= 1) { ps += __shfl_xor(ps, off); pd += __shfl_xor(pd, off); }
  if (lane == 0) { als[node] = ps; ald[node] = pd; }
}

// ---------------- layer-2 fused softmax + aggregate + ReLU + max-pool ----------------
// R5 structure: uniform-lane shuffles -> scalar-base coalesced row gathers.
__global__ __launch_bounds__(256)
void k_agg2(const __half* __restrict__ h2h, const float* __restrict__ als,
            const float* __restrict__ ald, const int* __restrict__ row_ptr,
            const int* __restrict__ csr_src, const float* __restrict__ b2,
            const int* __restrict__ batch, u32* __restrict__ pool) {
  int w = threadIdx.x >> 6, lane = threadIdx.x & 63;
  int node = blockIdx.x * 4 + w;
  int beg = row_ptr[node], end = row_ptr[node + 1];
  float aldn = ald[node];
  float ax = 0.f, ay = 0.f, ssum = 0.f;
  for (int base = beg; base < end; base += 64) {
    int cnt = min(64, end - base);
    int msrc = 0; float p = 0.f;
    if (lane < cnt) {
      msrc = csr_src[base + lane];
      float vv = als[msrc] + aldn;
      vv = vv > 0.f ? vv : 0.2f * vv;
      p = __expf(vv);
    }
    ssum += p;   // per-lane partial; reduced at end
    int j2 = 0;
    for (; j2 + 2 <= cnt; j2 += 2) {
      int sA = __shfl(msrc, j2), sB = __shfl(msrc, j2 + 1);
      float cA = __shfl(p, j2), cB = __shfl(p, j2 + 1);
      u32 ua = ((const u32*)(h2h + (size_t)sA * D2))[lane];
      u32 ub = ((const u32*)(h2h + (size_t)sB * D2))[lane];
      float2 f = h2f(ua); ax = fmaf(cA, f.x, ax); ay = fmaf(cA, f.y, ay);
      f = h2f(ub); ax = fmaf(cB, f.x, ax); ay = fmaf(cB, f.y, ay);
    }
    if (j2 < cnt) {
      int sA = __shfl(msrc, j2);
      float cA = __shfl(p, j2);
      u32 ua = ((const u32*)(h2h + (size_t)sA * D2))[lane];
      float2 f = h2f(ua); ax = fmaf(cA, f.x, ax); ay = fmaf(cA, f.y, ay);
    }
  }
  float t2 = ssum;
#pragma unroll
  for (int off = 32; off; off >>= 1) t2 += __shfl_xor(t2, off);
  float inv = 1.f / (t2 + 1e-16f);
  float2 bv = ((const float2*)b2)[lane];
  float vx = fmaxf(ax * inv + bv.x, 0.f);
  float vy = fmaxf(ay * inv + bv.y, 0.f);
  int g = batch[node];
  u32 bx = __float_as_uint(vx), by = __float_as_uint(vy);
  u32* p0 = pool + (size_t)g * D2 + 2 * lane;
  // monotonic non-negative pool: stale read only causes a redundant (safe) atomic
  if (bx > p0[0]) atomicMax(&p0[0], bx);
  if (by > p0[1]) atomicMax(&p0[1], by);
}

// ---------------- final FC + relu ----------------
__global__ void k_final(const float* __restrict__ pool, const float* __restrict__ fcw,
                        const float* __restrict__ fcb, float* __restrict__ out) {
  __shared__ float ps[D2];
  int g = blockIdx.x, j = threadIdx.x;
  ps[j] = pool[g * D2 + j];
  __syncthreads();
  float acc = 0.f;
  for (int c = 0; c < D2; c++) acc = fmaf(ps[c], fcw[c * D2 + j], acc);
  acc += fcb[j];
  out[g * D2 + j] = acc > 0.f ? acc : 0.f;
}

extern "C" void kernel_launch(void* const* d_in, const int* in_sizes, int n_in,
                              void* d_out, int out_size, void* d_ws, size_t ws_size,
                              hipStream_t stream) {
  const float* x     = (const float*)d_in[0];
  const int*   ei    = (const int*)d_in[1];
  const int*   batch = (const int*)d_in[2];
  const float* W1    = (const float*)d_in[3];
  const float* asrc1 = (const float*)d_in[4];
  const float* adst1 = (const float*)d_in[5];
  const float* b1    = (const float*)d_in[6];
  const float* W2    = (const float*)d_in[7];
  const float* asrc2 = (const float*)d_in[8];
  const float* adst2 = (const float*)d_in[9];
  const float* b2    = (const float*)d_in[10];
  const float* fcw   = (const float*)d_in[11];
  const float* fcb   = (const float*)d_in[12];
  float* out = (float*)d_out;

  char* w = (char*)d_ws;
  size_t off = 0;
  auto alloc = [&](size_t bytes) -> char* {
    char* p = w + off;
    off = (off + bytes + 255) & ~(size_t)255;
    return p;
  };
  int* counts    = (int*)alloc((size_t)N_NODES * 4);
  int* row_ptr   = (int*)alloc((size_t)(N_NODES + 1) * 4);
  int* nxt       = (int*)alloc((size_t)N_NODES * 4);
  int* csr_src   = (int*)alloc((size_t)E_TOT * 4);
  int* partial   = (int*)alloc(NCHUNK * 4);
  int* chunk_off = (int*)alloc(NCHUNK * 4);
  float* als1    = (float*)alloc((size_t)N_NODES * NH1 * 4);
  float* ald1    = (float*)alloc((size_t)N_NODES * NH1 * 4);
  float* als2    = (float*)alloc((size_t)N_NODES * 4);
  float* ald2    = (float*)alloc((size_t)N_NODES * 4);
  u32*   pool    = (u32*)alloc((size_t)N_GRAPHS * D2 * 4);
  float* w_als   = (float*)alloc((size_t)D1 * 4);
  float* w_ald   = (float*)alloc((size_t)D1 * 4);
  u32*   W1t2    = (u32*)alloc((size_t)D1 * (F_IN / 2) * 4);
  u32*   W2f     = (u32*)alloc((size_t)W2FW * 4);
  u32*   xh2     = (u32*)alloc((size_t)N_NODES * XW * 4);
  u32*   aggx2   = (u32*)alloc((size_t)N_NODES * (D1 / 2) * 4);
  __half* hacth  = (__half*)alloc((size_t)N_NODES * HPAD * 2);
  // aggx2 (36 MB) is dead after k_mix1 -> alias h2h (12.8 MB) into its region.
  // Keeps peak workspace ~86.6 MB, below the 97 MB proven safe in round 5.
  __half* h2h = (__half*)aggx2;

  k_init<<<dim3(196), dim3(256), 0, stream>>>(counts, pool);
  k_hist<<<dim3((E_TOT + 255) / 256), dim3(256), 0, stream>>>(ei, counts);
  k_scan1<<<dim3(NCHUNK), dim3(256), 0, stream>>>(counts, partial);
  k_scan2<<<dim3(1), dim3(64), 0, stream>>>(partial, chunk_off, row_ptr);
  k_scan3<<<dim3(NCHUNK), dim3(SCHUNK), 0, stream>>>(counts, chunk_off, row_ptr, nxt);
  k_scatter<<<dim3((E_TOT + 255) / 256), dim3(256), 0, stream>>>(ei, nxt, csr_src);
  k_prep<<<dim3(123), dim3(256), 0, stream>>>(W1, asrc1, adst1, W2, w_als, w_ald, W1t2, W2f);

  k_als1<<<dim3((N_NODES + 63) / 64), dim3(256), 0, stream>>>(x, w_als, w_ald, als1, ald1, xh2);
  k_agg1<<<dim3(N_NODES / 4), dim3(256), 0, stream>>>(xh2, als1, ald1, row_ptr, csr_src, aggx2);
  k_mix1<<<dim3((N_NODES + MIX_NPB - 1) / MIX_NPB), dim3(384), 0, stream>>>(aggx2, W1t2, b1, hacth);

  k_gemm2<<<dim3((N_NODES + 63) / 64), dim3(256), 0, stream>>>((const u32*)hacth, W2f, h2h);
  k_als2<<<dim3(N_NODES / 4), dim3(256), 0, stream>>>(h2h, asrc2, adst2, als2, ald2);
  k_agg2<<<dim3(N_NODES / 4), dim3(256), 0, stream>>>(h2h, als2, ald2, row_ptr, csr_src,
                                                      b2, batch, pool);

  k_final<<<dim3(N_GRAPHS), dim3(D2), 0, stream>>>((const float*)pool, fcw, fcb, out);

  (void)in_sizes; (void)n_in; (void)out_size; (void)ws_size;
}

// Round 13
// 458.115 us; speedup vs baseline: 1.9576x; 1.2046x over previous
//
#include <hip/hip_runtime.h>
#include <hip/hip_fp16.h>
#include <math.h>

#define N_NODES  50000
#define N_EDGES  800000
#define E_TOT    850000        // N_EDGES + N_NODES self loops
#define N_GRAPHS 128
#define F_IN     36
#define NH1      10
#define C1       36
#define D1       360           // NH1*C1
#define D2       128
#define XW       18            // u32 words per x row (36 halves)
#define HPAD     384           // hact padded K (halves)
#define KW       192           // u32 words per hact row
#define KCH      24            // k-chunks of 16
#define W2FW     24576         // u32 words in W2f fragment pack (8t*24kc*64l*4h /2)

#define SCHUNK  512
#define NCHUNK  98             // ceil(50000/512)

typedef unsigned int u32;

#if defined(__has_builtin)
#if __has_builtin(__builtin_amdgcn_fdot2)
#define HAVE_FDOT2 1
#endif
#endif
#ifndef HAVE_FDOT2
#define HAVE_FDOT2 0
#endif

typedef _Float16 h2v __attribute__((ext_vector_type(2)));
typedef _Float16 f16x4 __attribute__((ext_vector_type(4)));
typedef float f32x4 __attribute__((ext_vector_type(4)));

static __device__ __forceinline__ float2 h2f(u32 u) {
  __half2 h = __builtin_bit_cast(__half2, u);
  return __half22float2(h);
}
static __device__ __forceinline__ u32 f2h2(float a, float b) {
  __half2 h = __floats2half2_rn(a, b);
  return __builtin_bit_cast(u32, h);
}
static __device__ __forceinline__ float dot2acc(u32 a, u32 b, float acc) {
#if HAVE_FDOT2
  return __builtin_amdgcn_fdot2(__builtin_bit_cast(h2v, a), __builtin_bit_cast(h2v, b), acc, false);
#else
  float2 fa = h2f(a), fb = h2f(b);
  return fmaf(fa.x, fb.x, fmaf(fa.y, fb.y, acc));
#endif
}

// ---------------- init ----------------
__global__ void k_init(int* counts, u32* pool) {
  int i = blockIdx.x * blockDim.x + threadIdx.x;
  if (i < N_NODES) counts[i] = 0;
  if (i < N_GRAPHS * D2) pool[i] = 0u;
}

// ---------------- dst histogram ----------------
__global__ void k_hist(const int* ei, int* counts) {
  int e = blockIdx.x * blockDim.x + threadIdx.x;
  if (e >= E_TOT) return;
  int d = (e < N_EDGES) ? ei[N_EDGES + e] : (e - N_EDGES);
  atomicAdd(&counts[d], 1);
}

// ---------------- scan (3 kernels) ----------------
__global__ void k_scan1(const int* counts, int* partial) {
  __shared__ int red[256];
  int b = blockIdx.x, t = threadIdx.x;
  int base = b * SCHUNK;
  int v = 0;
  int i0 = base + t, i1 = base + t + 256;
  if (i0 < N_NODES) v += counts[i0];
  if (i1 < N_NODES) v += counts[i1];
  red[t] = v; __syncthreads();
  for (int off = 128; off; off >>= 1) {
    if (t < off) red[t] += red[t + off];
    __syncthreads();
  }
  if (t == 0) partial[b] = red[0];
}

__global__ void k_scan2(const int* partial, int* chunk_off, int* row_ptr) {
  if (threadIdx.x == 0 && blockIdx.x == 0) {
    int acc = 0;
    for (int i = 0; i < NCHUNK; i++) { chunk_off[i] = acc; acc += partial[i]; }
    row_ptr[N_NODES] = acc;
  }
}

__global__ void k_scan3(const int* counts, const int* chunk_off, int* row_ptr, int* nxt) {
  __shared__ int tmp[SCHUNK];
  int b = blockIdx.x, t = threadIdx.x;
  int i = b * SCHUNK + t;
  int v = (i < N_NODES) ? counts[i] : 0;
  tmp[t] = v; __syncthreads();
  for (int off = 1; off < SCHUNK; off <<= 1) {
    int x = (t >= off) ? tmp[t - off] : 0;
    __syncthreads();
    tmp[t] += x;
    __syncthreads();
  }
  if (i < N_NODES) {
    int excl = chunk_off[b] + tmp[t] - v;   // exclusive prefix
    row_ptr[i] = excl;
    nxt[i] = excl;
  }
}

// ---------------- scatter edges into CSR by dst ----------------
__global__ void k_scatter(const int* ei, int* nxt, int* csr_src) {
  int e = blockIdx.x * blockDim.x + threadIdx.x;
  if (e >= E_TOT) return;
  int s, d;
  if (e < N_EDGES) { s = ei[e]; d = ei[N_EDGES + e]; }
  else             { s = d = e - N_EDGES; }
  int pos = atomicAdd(&nxt[d], 1);
  csr_src[pos] = s;
}

// ---------------- merged weight prep: w_als/w_ald + W1t2 + W2f ----------------
// ids: D1 (360) + D1*18 (6480) + W2FW (24576) = 31416 -> 123 blocks x 256
__global__ void k_prep(const float* __restrict__ W1, const float* __restrict__ asrc,
                       const float* __restrict__ adst, const float* __restrict__ W2,
                       float* w_als, float* w_ald, u32* W1t2, u32* W2f) {
  int id = blockIdx.x * blockDim.x + threadIdx.x;
  if (id < D1) {
    // w_als[h*36+k] = sum_c W1[k, h*36+c]*a_src[h,c]
    int h = id / F_IN, k = id - h * F_IN;
    float sa = 0.f, sd = 0.f;
    for (int c = 0; c < C1; c++) {
      float wv = W1[k * D1 + h * C1 + c];
      sa = fmaf(wv, asrc[h * C1 + c], sa);
      sd = fmaf(wv, adst[h * C1 + c], sd);
    }
    w_als[id] = sa; w_ald[id] = sd;
  } else if (id < D1 + D1 * (F_IN / 2)) {
    // W1 transposed + k-paired fp16: W1t2[hc][kp]
    int i = id - D1;
    int hc = i / (F_IN / 2), kp = i - hc * (F_IN / 2);
    W1t2[i] = f2h2(W1[(2 * kp) * D1 + hc], W1[(2 * kp + 1) * D1 + hc]);
  } else if (id < D1 + D1 * (F_IN / 2) + W2FW) {
    // W2 in exact mfma_16x16x16f16 B-fragment order:
    // uint2 index (kc*8+t)*64+lane holds B[k = kc*16+4*(lane>>4)+j][col = 16t+(lane&15)], j=0..3
    int i = id - D1 - D1 * (F_IN / 2);
    int q    = i & 1;           // half-pair within lane's 4 halves
    int lane = (i >> 1) & 63;
    int rem  = i >> 7;
    int t    = rem & 7;
    int kc   = rem >> 3;        // 0..23
    int k0   = kc * 16 + ((lane >> 4) << 2) + 2 * q;
    int col  = t * 16 + (lane & 15);
    float w0 = (k0     < D1) ? W2[(size_t)k0 * D2 + col]       : 0.f;
    float w1 = (k0 + 1 < D1) ? W2[(size_t)(k0 + 1) * D2 + col] : 0.f;
    W2f[i] = f2h2(w0, w1);
  }
}

// ---------------- layer-1 attention scalars + x fp16 pack ----------------
__global__ __launch_bounds__(256)
void k_als1(const float* __restrict__ x, const float* __restrict__ w_als,
            const float* __restrict__ w_ald, float* als, float* ald,
            u32* __restrict__ xh2) {
  __shared__ float xs[64][F_IN + 1];
  __shared__ float wa[D1], wd[D1];
  int t = threadIdx.x;
  int nb = blockIdx.x * 64;
  for (int i = t; i < D1; i += 256) { wa[i] = w_als[i]; wd[i] = w_ald[i]; }
  int lim = min(64, N_NODES - nb);
  for (int i = t; i < lim * F_IN; i += 256) {
    int n = i / F_IN, k = i - n * F_IN;
    xs[n][k] = x[(size_t)(nb + n) * F_IN + k];
  }
  __syncthreads();
  // pack x -> fp16 pairs
  for (int i = t; i < lim * XW; i += 256) {
    int n = i / XW, kp = i - n * XW;
    xh2[(size_t)(nb + n) * XW + kp] = f2h2(xs[n][2 * kp], xs[n][2 * kp + 1]);
  }
  for (int pair = t; pair < lim * NH1; pair += 256) {
    int n = pair / NH1, h = pair - n * NH1;
    const float* xp = xs[n];
    const float* wap = &wa[h * F_IN];
    const float* wdp = &wd[h * F_IN];
    float sa = 0.f, sd = 0.f;
#pragma unroll
    for (int k = 0; k < F_IN; k++) {
      float xv = xp[k];
      sa = fmaf(xv, wap[k], sa);
      sd = fmaf(xv, wdp[k], sd);
    }
    als[(size_t)(nb + n) * NH1 + h] = sa;
    ald[(size_t)(nb + n) * NH1 + h] = sd;
  }
}

// ---------------- layer-1 fused softmax + x-aggregation (per node, 1 wave) ----------------
// acc u32-slot s = h*18+kp (halves h*36+2kp, +1); lane owns s in {lane, lane+64, lane+128}
__global__ __launch_bounds__(256)
void k_agg1(const u32* __restrict__ xrow, const float* __restrict__ als,
            const float* __restrict__ ald, const int* __restrict__ row_ptr,
            const int* __restrict__ csr_src, u32* __restrict__ aggx2) {
  __shared__ float pl[4][64][NH1];
  int w = threadIdx.x >> 6, lane = threadIdx.x & 63;
  int node = blockIdx.x * 4 + w;     // 50000 = 4*12500 exact
  int beg = row_ptr[node], end = row_ptr[node + 1];

  int h0 = lane / XW,  kp0 = lane - XW * h0;
  int s1 = lane + 64;
  int h1i = s1 / XW,   kp1 = s1 - XW * h1i;
  bool v2 = lane < 52;               // slot lane+128 < 180
  int s2 = v2 ? lane + 128 : 179;
  int h2i = s2 / XW,   kp2 = s2 - XW * h2i;

  float aldn[NH1];
#pragma unroll
  for (int h = 0; h < NH1; h++) aldn[h] = ald[(size_t)node * NH1 + h];
  float a0x = 0.f, a0y = 0.f, a1x = 0.f, a1y = 0.f, a2x = 0.f, a2y = 0.f;
  float sp[NH1];
#pragma unroll
  for (int h = 0; h < NH1; h++) sp[h] = 0.f;

  for (int base = beg; base < end; base += 64) {
    int cnt = min(64, end - base);
    float p[NH1];
    int msrc = 0;
    if (lane < cnt) {
      msrc = csr_src[base + lane];
      const float2* ap = (const float2*)(als + (size_t)msrc * NH1);
#pragma unroll
      for (int q = 0; q < 5; q++) {
        float2 v = ap[q];
        float v0 = v.x + aldn[2 * q];
        float v1 = v.y + aldn[2 * q + 1];
        v0 = v0 > 0.f ? v0 : 0.2f * v0;     // leaky_relu
        v1 = v1 > 0.f ? v1 : 0.2f * v1;
        p[2 * q] = __expf(v0);              // no max-shift: logits O(1)
        p[2 * q + 1] = __expf(v1);
      }
    } else {
#pragma unroll
      for (int h = 0; h < NH1; h++) p[h] = 0.f;
    }
#pragma unroll
    for (int h = 0; h < NH1; h++) sp[h] += p[h];
    float2* plw = (float2*)pl[w][lane];
#pragma unroll
    for (int q = 0; q < 5; q++) plw[q] = float2{p[2 * q], p[2 * q + 1]};
    __builtin_amdgcn_wave_barrier();

    int j2 = 0;
    for (; j2 + 4 <= cnt; j2 += 4) {
      int sA = __shfl(msrc, j2),     sB = __shfl(msrc, j2 + 1);
      int sC = __shfl(msrc, j2 + 2), sD = __shfl(msrc, j2 + 3);
      const u32* ra = xrow + (size_t)sA * XW;
      const u32* rb = xrow + (size_t)sB * XW;
      const u32* rc = xrow + (size_t)sC * XW;
      const u32* rd = xrow + (size_t)sD * XW;
      u32 ua0 = ra[kp0], ua1 = ra[kp1], ua2 = ra[kp2];
      u32 ub0 = rb[kp0], ub1 = rb[kp1], ub2 = rb[kp2];
      u32 uc0 = rc[kp0], uc1 = rc[kp1], uc2 = rc[kp2];
      u32 ud0 = rd[kp0], ud1 = rd[kp1], ud2 = rd[kp2];
      const float* pA = pl[w][j2];
      const float* pB = pl[w][j2 + 1];
      const float* pC = pl[w][j2 + 2];
      const float* pD = pl[w][j2 + 3];
      float cA0 = pA[h0], cA1 = pA[h1i], cA2 = pA[h2i];
      float cB0 = pB[h0], cB1 = pB[h1i], cB2 = pB[h2i];
      float cC0 = pC[h0], cC1 = pC[h1i], cC2 = pC[h2i];
      float cD0 = pD[h0], cD1 = pD[h1i], cD2 = pD[h2i];
      float2 f;
      f = h2f(ua0); a0x = fmaf(cA0, f.x, a0x); a0y = fmaf(cA0, f.y, a0y);
      f = h2f(ua1); a1x = fmaf(cA1, f.x, a1x); a1y = fmaf(cA1, f.y, a1y);
      f = h2f(ua2); a2x = fmaf(cA2, f.x, a2x); a2y = fmaf(cA2, f.y, a2y);
      f = h2f(ub0); a0x = fmaf(cB0, f.x, a0x); a0y = fmaf(cB0, f.y, a0y);
      f = h2f(ub1); a1x = fmaf(cB1, f.x, a1x); a1y = fmaf(cB1, f.y, a1y);
      f = h2f(ub2); a2x = fmaf(cB2, f.x, a2x); a2y = fmaf(cB2, f.y, a2y);
      f = h2f(uc0); a0x = fmaf(cC0, f.x, a0x); a0y = fmaf(cC0, f.y, a0y);
      f = h2f(uc1); a1x = fmaf(cC1, f.x, a1x); a1y = fmaf(cC1, f.y, a1y);
      f = h2f(uc2); a2x = fmaf(cC2, f.x, a2x); a2y = fmaf(cC2, f.y, a2y);
      f = h2f(ud0); a0x = fmaf(cD0, f.x, a0x); a0y = fmaf(cD0, f.y, a0y);
      f = h2f(ud1); a1x = fmaf(cD1, f.x, a1x); a1y = fmaf(cD1, f.y, a1y);
      f = h2f(ud2); a2x = fmaf(cD2, f.x, a2x); a2y = fmaf(cD2, f.y, a2y);
    }
    for (; j2 < cnt; j2++) {
      int sA = __shfl(msrc, j2);
      const u32* ra = xrow + (size_t)sA * XW;
      u32 ua0 = ra[kp0], ua1 = ra[kp1], ua2 = ra[kp2];
      const float* pA = pl[w][j2];
      float cA0 = pA[h0], cA1 = pA[h1i], cA2 = pA[h2i];
      float2 f;
      f = h2f(ua0); a0x = fmaf(cA0, f.x, a0x); a0y = fmaf(cA0, f.y, a0y);
      f = h2f(ua1); a1x = fmaf(cA1, f.x, a1x); a1y = fmaf(cA1, f.y, a1y);
      f = h2f(ua2); a2x = fmaf(cA2, f.x, a2x); a2y = fmaf(cA2, f.y, a2y);
    }
    __builtin_amdgcn_wave_barrier();
  }

  // reduce per-lane partial sums -> softmax denominators
#pragma unroll
  for (int h = 0; h < NH1; h++) {
    float t = sp[h];
#pragma unroll
    for (int off = 32; off; off >>= 1) t += __shfl_xor(t, off);
    sp[h] = t;
  }
  float i0 = 1.f / (sp[h0] + 1e-16f);
  float i1 = 1.f / (sp[h1i] + 1e-16f);
  float i2 = 1.f / (sp[h2i] + 1e-16f);
  u32* orow = aggx2 + (size_t)node * (D1 / 2);
  orow[lane] = f2h2(a0x * i0, a0y * i0);
  orow[lane + 64] = f2h2(a1x * i1, a1y * i1);
  if (v2) orow[lane + 128] = f2h2(a2x * i2, a2y * i2);
}

// ---------------- mix1: hact[n,hc] = ELU( sum_k agg[n,h,k]*W1[k,hc] + b1[hc] ), K-padded to 384 ----------------
#define MIX_NPB 32
__global__ __launch_bounds__(384)
void k_mix1(const u32* __restrict__ aggx2, const u32* __restrict__ W1t2,
            const float* __restrict__ b1, __half* __restrict__ hact) {
  __shared__ u32 ag[MIX_NPB][D1 / 2 + 4];
  int t = threadIdx.x;
  int nb = blockIdx.x * MIX_NPB;
  int lim = min(MIX_NPB, N_NODES - nb);
  const u32* gsrc = aggx2 + (size_t)nb * (D1 / 2);
  for (int i = t; i < lim * (D1 / 2); i += 384) {
    int n = i / (D1 / 2), k = i - n * (D1 / 2);
    ag[n][k] = gsrc[i];
  }
  __syncthreads();
  if (t < D1) {
    int h = t / C1;
    u32 wreg[F_IN / 2];
#pragma unroll
    for (int kp = 0; kp < F_IN / 2; kp++) wreg[kp] = W1t2[t * (F_IN / 2) + kp];
    float bj = b1[t];
    for (int n = 0; n < lim; n++) {
      const u32* a = &ag[n][h * (F_IN / 2)];
      float acc2 = 0.f;
#pragma unroll
      for (int kp = 0; kp < F_IN / 2; kp++) acc2 = dot2acc(a[kp], wreg[kp], acc2);
      float val = acc2 + bj;
      val = val > 0.f ? val : __expf(val) - 1.f;   // ELU
      hact[(size_t)(nb + n) * HPAD + t] = __float2half(val);
    }
  } else {
    // zero-fill K padding [360,384)
    for (int n = 0; n < lim; n++)
      hact[(size_t)(nb + n) * HPAD + t] = __float2half(0.f);
  }
}

// ---------------- GEMM2 via MFMA: h2 = hact @ W2  [N,128] ----------------
// v_mfma_f32_16x16x16f16: A lane l holds A[l&15][4*(l>>4)+j]; D: col=lane&15, row=4*(lane>>4)+r.
// Block = 4 waves x 16 rows = 64 rows; each wave does all 8 col-tiles over 24 k-chunks.
__global__ __launch_bounds__(256)
void k_gemm2(const u32* __restrict__ hact32, const u32* __restrict__ W2f,
             __half* __restrict__ h2h) {
  int w = threadIdx.x >> 6, l = threadIdx.x & 63;
  int rowbase = blockIdx.x * 64 + w * 16;
  int m = l & 15, kb = l >> 4;
  int arow = rowbase + m;
  if (arow >= N_NODES) arow = N_NODES - 1;     // clamp loads; stores guarded
  const u32* ap = hact32 + (size_t)arow * KW + kb * 2;
  const uint2* bp = (const uint2*)W2f;
  f32x4 acc[8];
#pragma unroll
  for (int t = 0; t < 8; t++) acc[t] = (f32x4){0.f, 0.f, 0.f, 0.f};
#pragma unroll 4
  for (int kc = 0; kc < KCH; kc++) {
    uint2 aw = *(const uint2*)(ap + kc * 8);
    f16x4 af = __builtin_bit_cast(f16x4, aw);
#pragma unroll
    for (int t = 0; t < 8; t++) {
      uint2 bw = bp[(kc * 8 + t) * 64 + l];
      acc[t] = __builtin_amdgcn_mfma_f32_16x16x16f16(af, __builtin_bit_cast(f16x4, bw),
                                                     acc[t], 0, 0, 0);
    }
  }
  int orow0 = rowbase + (l >> 4) * 4;
  int col0 = l & 15;
#pragma unroll
  for (int t = 0; t < 8; t++) {
#pragma unroll
    for (int r = 0; r < 4; r++) {
      int row = orow0 + r;
      if (row < N_NODES)
        h2h[(size_t)row * D2 + t * 16 + col0] = __float2half(acc[t][r]);
    }
  }
}

// ---------------- attention scalars, layer 2 ----------------
__global__ void k_als2(const __half* __restrict__ h2h, const float* __restrict__ asrc,
                       const float* __restrict__ adst, float* als, float* ald) {
  int node = blockIdx.x * 4 + (threadIdx.x >> 6);
  int lane = threadIdx.x & 63;
  const u32* hr = (const u32*)(h2h + (size_t)node * D2);
  float2 f = h2f(hr[lane]);
  float2 a = ((const float2*)asrc)[lane];
  float2 d = ((const float2*)adst)[lane];
  float ps = f.x * a.x + f.y * a.y;
  float pd = f.x * d.x + f.y * d.y;
#pragma unroll
  for (int off = 32; off; off >>= 1) { ps += __shfl_xor(ps, off); pd += __shfl_xor(pd, off); }
  if (lane == 0) { als[node] = ps; ald[node] = pd; }
}

// ---------------- layer-2 fused softmax + aggregate + ReLU + max-pool ----------------
// R5 structure: uniform-lane shuffles -> scalar-base coalesced row gathers.
// A/B vs R12: epilogue reverted to UNCONDITIONAL atomicMax (R5-proven 98us form).
__global__ __launch_bounds__(256)
void k_agg2(const __half* __restrict__ h2h, const float* __restrict__ als,
            const float* __restrict__ ald, const int* __restrict__ row_ptr,
            const int* __restrict__ csr_src, const float* __restrict__ b2,
            const int* __restrict__ batch, u32* __restrict__ pool) {
  int w = threadIdx.x >> 6, lane = threadIdx.x & 63;
  int node = blockIdx.x * 4 + w;
  int beg = row_ptr[node], end = row_ptr[node + 1];
  float aldn = ald[node];
  float ax = 0.f, ay = 0.f, ssum = 0.f;
  for (int base = beg; base < end; base += 64) {
    int cnt = min(64, end - base);
    int msrc = 0; float p = 0.f;
    if (lane < cnt) {
      msrc = csr_src[base + lane];
      float vv = als[msrc] + aldn;
      vv = vv > 0.f ? vv : 0.2f * vv;
      p = __expf(vv);
    }
    ssum += p;   // per-lane partial; reduced at end
    int j2 = 0;
    for (; j2 + 2 <= cnt; j2 += 2) {
      int sA = __shfl(msrc, j2), sB = __shfl(msrc, j2 + 1);
      float cA = __shfl(p, j2), cB = __shfl(p, j2 + 1);
      u32 ua = ((const u32*)(h2h + (size_t)sA * D2))[lane];
      u32 ub = ((const u32*)(h2h + (size_t)sB * D2))[lane];
      float2 f = h2f(ua); ax = fmaf(cA, f.x, ax); ay = fmaf(cA, f.y, ay);
      f = h2f(ub); ax = fmaf(cB, f.x, ax); ay = fmaf(cB, f.y, ay);
    }
    if (j2 < cnt) {
      int sA = __shfl(msrc, j2);
      float cA = __shfl(p, j2);
      u32 ua = ((const u32*)(h2h + (size_t)sA * D2))[lane];
      float2 f = h2f(ua); ax = fmaf(cA, f.x, ax); ay = fmaf(cA, f.y, ay);
    }
  }
  float t2 = ssum;
#pragma unroll
  for (int off = 32; off; off >>= 1) t2 += __shfl_xor(t2, off);
  float inv = 1.f / (t2 + 1e-16f);
  float2 bv = ((const float2*)b2)[lane];
  float vx = fmaxf(ax * inv + bv.x, 0.f);
  float vy = fmaxf(ay * inv + bv.y, 0.f);
  int g = batch[node];
  atomicMax(&pool[(size_t)g * D2 + 2 * lane],     __float_as_uint(vx));
  atomicMax(&pool[(size_t)g * D2 + 2 * lane + 1], __float_as_uint(vy));
}

// ---------------- final FC + relu ----------------
__global__ void k_final(const float* __restrict__ pool, const float* __restrict__ fcw,
                        const float* __restrict__ fcb, float* __restrict__ out) {
  __shared__ float ps[D2];
  int g = blockIdx.x, j = threadIdx.x;
  ps[j] = pool[g * D2 + j];
  __syncthreads();
  float acc = 0.f;
  for (int c = 0; c < D2; c++) acc = fmaf(ps[c], fcw[c * D2 + j], acc);
  acc += fcb[j];
  out[g * D2 + j] = acc > 0.f ? acc : 0.f;
}

extern "C" void kernel_launch(void* const* d_in, const int* in_sizes, int n_in,
                              void* d_out, int out_size, void* d_ws, size_t ws_size,
                              hipStream_t stream) {
  const float* x     = (const float*)d_in[0];
  const int*   ei    = (const int*)d_in[1];
  const int*   batch = (const int*)d_in[2];
  const float* W1    = (const float*)d_in[3];
  const float* asrc1 = (const float*)d_in[4];
  const float* adst1 = (const float*)d_in[5];
  const float* b1    = (const float*)d_in[6];
  const float* W2    = (const float*)d_in[7];
  const float* asrc2 = (const float*)d_in[8];
  const float* adst2 = (const float*)d_in[9];
  const float* b2    = (const float*)d_in[10];
  const float* fcw   = (const float*)d_in[11];
  const float* fcb   = (const float*)d_in[12];
  float* out = (float*)d_out;

  char* w = (char*)d_ws;
  size_t off = 0;
  auto alloc = [&](size_t bytes) -> char* {
    char* p = w + off;
    off = (off + bytes + 255) & ~(size_t)255;
    return p;
  };
  int* counts    = (int*)alloc((size_t)N_NODES * 4);
  int* row_ptr   = (int*)alloc((size_t)(N_NODES + 1) * 4);
  int* nxt       = (int*)alloc((size_t)N_NODES * 4);
  int* csr_src   = (int*)alloc((size_t)E_TOT * 4);
  int* partial   = (int*)alloc(NCHUNK * 4);
  int* chunk_off = (int*)alloc(NCHUNK * 4);
  float* als1    = (float*)alloc((size_t)N_NODES * NH1 * 4);
  float* ald1    = (float*)alloc((size_t)N_NODES * NH1 * 4);
  float* als2    = (float*)alloc((size_t)N_NODES * 4);
  float* ald2    = (float*)alloc((size_t)N_NODES * 4);
  u32*   pool    = (u32*)alloc((size_t)N_GRAPHS * D2 * 4);
  float* w_als   = (float*)alloc((size_t)D1 * 4);
  float* w_ald   = (float*)alloc((size_t)D1 * 4);
  u32*   W1t2    = (u32*)alloc((size_t)D1 * (F_IN / 2) * 4);
  u32*   W2f     = (u32*)alloc((size_t)W2FW * 4);
  u32*   xh2     = (u32*)alloc((size_t)N_NODES * XW * 4);
  u32*   aggx2   = (u32*)alloc((size_t)N_NODES * (D1 / 2) * 4);
  __half* hacth  = (__half*)alloc((size_t)N_NODES * HPAD * 2);
  // aggx2 (36 MB) is dead after k_mix1 -> alias h2h (12.8 MB) into its region.
  // Keeps peak workspace ~86.6 MB, below the 97 MB proven safe in round 5.
  __half* h2h = (__half*)aggx2;

  k_init<<<dim3(196), dim3(256), 0, stream>>>(counts, pool);
  k_hist<<<dim3((E_TOT + 255) / 256), dim3(256), 0, stream>>>(ei, counts);
  k_scan1<<<dim3(NCHUNK), dim3(256), 0, stream>>>(counts, partial);
  k_scan2<<<dim3(1), dim3(64), 0, stream>>>(partial, chunk_off, row_ptr);
  k_scan3<<<dim3(NCHUNK), dim3(SCHUNK), 0, stream>>>(counts, chunk_off, row_ptr, nxt);
  k_scatter<<<dim3((E_TOT + 255) / 256), dim3(256), 0, stream>>>(ei, nxt, csr_src);
  k_prep<<<dim3(123), dim3(256), 0, stream>>>(W1, asrc1, adst1, W2, w_als, w_ald, W1t2, W2f);

  k_als1<<<dim3((N_NODES + 63) / 64), dim3(256), 0, stream>>>(x, w_als, w_ald, als1, ald1, xh2);
  k_agg1<<<dim3(N_NODES / 4), dim3(256), 0, stream>>>(xh2, als1, ald1, row_ptr, csr_src, aggx2);
  k_mix1<<<dim3((N_NODES + MIX_NPB - 1) / MIX_NPB), dim3(384), 0, stream>>>(aggx2, W1t2, b1, hacth);

  k_gemm2<<<dim3((N_NODES + 63) / 64), dim3(256), 0, stream>>>((const u32*)hacth, W2f, h2h);
  k_als2<<<dim3(N_NODES / 4), dim3(256), 0, stream>>>(h2h, asrc2, adst2, als2, ald2);
  k_agg2<<<dim3(N_NODES / 4), dim3(256), 0, stream>>>(h2h, als2, ald2, row_ptr, csr_src,
                                                      b2, batch, pool);

  k_final<<<dim3(N_GRAPHS), dim3(D2), 0, stream>>>((const float*)pool, fcw, fcb, out);

  (void)in_sizes; (void)n_in; (void)out_size; (void)ws_size;
}

// Round 14
// 444.429 us; speedup vs baseline: 2.0179x; 1.0308x over previous
//
#include <hip/hip_runtime.h>
#include <hip/hip_fp16.h>
#include <math.h>

#define N_NODES  50000
#define N_EDGES  800000
#define E_TOT    850000        // N_EDGES + N_NODES self loops
#define N_GRAPHS 128
#define F_IN     36
#define NH1      10
#define C1       36
#define D1       360           // NH1*C1
#define D2       128
#define XW       18            // u32 words per x row (36 halves)
#define HPAD     384           // hact padded K (halves)
#define KW       192           // u32 words per hact row
#define KCH      24            // k-chunks of 16
#define W2FW     24576         // u32 words in W2f fragment pack

#define SCHUNK  512
#define NCHUNK  98             // ceil(50000/512)

typedef unsigned int u32;

#if defined(__has_builtin)
#if __has_builtin(__builtin_amdgcn_fdot2)
#define HAVE_FDOT2 1
#endif
#endif
#ifndef HAVE_FDOT2
#define HAVE_FDOT2 0
#endif

typedef _Float16 h2v __attribute__((ext_vector_type(2)));
typedef _Float16 f16x4 __attribute__((ext_vector_type(4)));
typedef float f32x4 __attribute__((ext_vector_type(4)));

static __device__ __forceinline__ float2 h2f(u32 u) {
  __half2 h = __builtin_bit_cast(__half2, u);
  return __half22float2(h);
}
static __device__ __forceinline__ u32 f2h2(float a, float b) {
  __half2 h = __floats2half2_rn(a, b);
  return __builtin_bit_cast(u32, h);
}
static __device__ __forceinline__ float dot2acc(u32 a, u32 b, float acc) {
#if HAVE_FDOT2
  return __builtin_amdgcn_fdot2(__builtin_bit_cast(h2v, a), __builtin_bit_cast(h2v, b), acc, false);
#else
  float2 fa = h2f(a), fb = h2f(b);
  return fmaf(fa.x, fb.x, fmaf(fa.y, fb.y, acc));
#endif
}

// ---------------- init ----------------
__global__ void k_init(int* counts, u32* pool) {
  int i = blockIdx.x * blockDim.x + threadIdx.x;
  if (i < N_NODES) counts[i] = 0;
  if (i < N_GRAPHS * D2) pool[i] = 0u;
}

// ---------------- dst histogram ----------------
__global__ void k_hist(const int* ei, int* counts) {
  int e = blockIdx.x * blockDim.x + threadIdx.x;
  if (e >= E_TOT) return;
  int d = (e < N_EDGES) ? ei[N_EDGES + e] : (e - N_EDGES);
  atomicAdd(&counts[d], 1);
}

// ---------------- scan (3 kernels) ----------------
__global__ void k_scan1(const int* counts, int* partial) {
  __shared__ int red[256];
  int b = blockIdx.x, t = threadIdx.x;
  int base = b * SCHUNK;
  int v = 0;
  int i0 = base + t, i1 = base + t + 256;
  if (i0 < N_NODES) v += counts[i0];
  if (i1 < N_NODES) v += counts[i1];
  red[t] = v; __syncthreads();
  for (int off = 128; off; off >>= 1) {
    if (t < off) red[t] += red[t + off];
    __syncthreads();
  }
  if (t == 0) partial[b] = red[0];
}

__global__ void k_scan2(const int* partial, int* chunk_off, int* row_ptr) {
  if (threadIdx.x == 0 && blockIdx.x == 0) {
    int acc = 0;
    for (int i = 0; i < NCHUNK; i++) { chunk_off[i] = acc; acc += partial[i]; }
    row_ptr[N_NODES] = acc;
  }
}

__global__ void k_scan3(const int* counts, const int* chunk_off, int* row_ptr, int* nxt) {
  __shared__ int tmp[SCHUNK];
  int b = blockIdx.x, t = threadIdx.x;
  int i = b * SCHUNK + t;
  int v = (i < N_NODES) ? counts[i] : 0;
  tmp[t] = v; __syncthreads();
  for (int off = 1; off < SCHUNK; off <<= 1) {
    int x = (t >= off) ? tmp[t - off] : 0;
    __syncthreads();
    tmp[t] += x;
    __syncthreads();
  }
  if (i < N_NODES) {
    int excl = chunk_off[b] + tmp[t] - v;   // exclusive prefix
    row_ptr[i] = excl;
    nxt[i] = excl;
  }
}

// ---------------- scatter edges into CSR by dst ----------------
__global__ void k_scatter(const int* ei, int* nxt, int* csr_src) {
  int e = blockIdx.x * blockDim.x + threadIdx.x;
  if (e >= E_TOT) return;
  int s, d;
  if (e < N_EDGES) { s = ei[e]; d = ei[N_EDGES + e]; }
  else             { s = d = e - N_EDGES; }
  int pos = atomicAdd(&nxt[d], 1);
  csr_src[pos] = s;
}

// ---------------- merged weight prep: w_als/w_ald + W1t2 + W2f ----------------
// ids: D1 (360) + D1*18 (6480) + W2FW (24576) = 31416 -> 123 blocks x 256
__global__ void k_prep(const float* __restrict__ W1, const float* __restrict__ asrc,
                       const float* __restrict__ adst, const float* __restrict__ W2,
                       float* w_als, float* w_ald, u32* W1t2, u32* W2f) {
  int id = blockIdx.x * blockDim.x + threadIdx.x;
  if (id < D1) {
    // w_als[h*36+k] = sum_c W1[k, h*36+c]*a_src[h,c]
    int h = id / F_IN, k = id - h * F_IN;
    float sa = 0.f, sd = 0.f;
    for (int c = 0; c < C1; c++) {
      float wv = W1[k * D1 + h * C1 + c];
      sa = fmaf(wv, asrc[h * C1 + c], sa);
      sd = fmaf(wv, adst[h * C1 + c], sd);
    }
    w_als[id] = sa; w_ald[id] = sd;
  } else if (id < D1 + D1 * (F_IN / 2)) {
    // W1 transposed + k-paired fp16: W1t2[hc][kp]
    int i = id - D1;
    int hc = i / (F_IN / 2), kp = i - hc * (F_IN / 2);
    W1t2[i] = f2h2(W1[(2 * kp) * D1 + hc], W1[(2 * kp + 1) * D1 + hc]);
  } else if (id < D1 + D1 * (F_IN / 2) + W2FW) {
    // W2 in exact mfma_16x16x16f16 B-fragment order:
    // uint2 index (kc*8+t)*64+lane holds B[k = kc*16+4*(lane>>4)+j][col = 16t+(lane&15)], j=0..3
    int i = id - D1 - D1 * (F_IN / 2);
    int q    = i & 1;           // half-pair within lane's 4 halves
    int lane = (i >> 1) & 63;
    int rem  = i >> 7;
    int t    = rem & 7;
    int kc   = rem >> 3;        // 0..23
    int k0   = kc * 16 + ((lane >> 4) << 2) + 2 * q;
    int col  = t * 16 + (lane & 15);
    float w0 = (k0     < D1) ? W2[(size_t)k0 * D2 + col]       : 0.f;
    float w1 = (k0 + 1 < D1) ? W2[(size_t)(k0 + 1) * D2 + col] : 0.f;
    W2f[i] = f2h2(w0, w1);
  }
}

// ---------------- layer-1 attention scalars + x fp16 pack ----------------
__global__ __launch_bounds__(256)
void k_als1(const float* __restrict__ x, const float* __restrict__ w_als,
            const float* __restrict__ w_ald, float* als, float* ald,
            u32* __restrict__ xh2) {
  __shared__ float xs[64][F_IN + 1];
  __shared__ float wa[D1], wd[D1];
  int t = threadIdx.x;
  int nb = blockIdx.x * 64;
  for (int i = t; i < D1; i += 256) { wa[i] = w_als[i]; wd[i] = w_ald[i]; }
  int lim = min(64, N_NODES - nb);
  for (int i = t; i < lim * F_IN; i += 256) {
    int n = i / F_IN, k = i - n * F_IN;
    xs[n][k] = x[(size_t)(nb + n) * F_IN + k];
  }
  __syncthreads();
  // pack x -> fp16 pairs
  for (int i = t; i < lim * XW; i += 256) {
    int n = i / XW, kp = i - n * XW;
    xh2[(size_t)(nb + n) * XW + kp] = f2h2(xs[n][2 * kp], xs[n][2 * kp + 1]);
  }
  for (int pair = t; pair < lim * NH1; pair += 256) {
    int n = pair / NH1, h = pair - n * NH1;
    const float* xp = xs[n];
    const float* wap = &wa[h * F_IN];
    const float* wdp = &wd[h * F_IN];
    float sa = 0.f, sd = 0.f;
#pragma unroll
    for (int k = 0; k < F_IN; k++) {
      float xv = xp[k];
      sa = fmaf(xv, wap[k], sa);
      sd = fmaf(xv, wdp[k], sd);
    }
    als[(size_t)(nb + n) * NH1 + h] = sa;
    ald[(size_t)(nb + n) * NH1 + h] = sd;
  }
}

// ---------------- layer-1 fused softmax + x-aggregation (per node, 1 wave) ----------------
// acc u32-slot s = h*18+kp (halves h*36+2kp, +1); lane owns s in {lane, lane+64, lane+128}
__global__ __launch_bounds__(256)
void k_agg1(const u32* __restrict__ xrow, const float* __restrict__ als,
            const float* __restrict__ ald, const int* __restrict__ row_ptr,
            const int* __restrict__ csr_src, u32* __restrict__ aggx2) {
  __shared__ float pl[4][64][NH1];
  int w = threadIdx.x >> 6, lane = threadIdx.x & 63;
  int node = blockIdx.x * 4 + w;     // 50000 = 4*12500 exact
  int beg = row_ptr[node], end = row_ptr[node + 1];

  int h0 = lane / XW,  kp0 = lane - XW * h0;
  int s1 = lane + 64;
  int h1i = s1 / XW,   kp1 = s1 - XW * h1i;
  bool v2 = lane < 52;               // slot lane+128 < 180
  int s2 = v2 ? lane + 128 : 179;
  int h2i = s2 / XW,   kp2 = s2 - XW * h2i;

  float aldn[NH1];
#pragma unroll
  for (int h = 0; h < NH1; h++) aldn[h] = ald[(size_t)node * NH1 + h];
  float a0x = 0.f, a0y = 0.f, a1x = 0.f, a1y = 0.f, a2x = 0.f, a2y = 0.f;
  float sp[NH1];
#pragma unroll
  for (int h = 0; h < NH1; h++) sp[h] = 0.f;

  for (int base = beg; base < end; base += 64) {
    int cnt = min(64, end - base);
    float p[NH1];
    int msrc = 0;
    if (lane < cnt) {
      msrc = csr_src[base + lane];
      const float2* ap = (const float2*)(als + (size_t)msrc * NH1);
#pragma unroll
      for (int q = 0; q < 5; q++) {
        float2 v = ap[q];
        float v0 = v.x + aldn[2 * q];
        float v1 = v.y + aldn[2 * q + 1];
        v0 = v0 > 0.f ? v0 : 0.2f * v0;     // leaky_relu
        v1 = v1 > 0.f ? v1 : 0.2f * v1;
        p[2 * q] = __expf(v0);              // no max-shift: logits O(1)
        p[2 * q + 1] = __expf(v1);
      }
    } else {
#pragma unroll
      for (int h = 0; h < NH1; h++) p[h] = 0.f;
    }
#pragma unroll
    for (int h = 0; h < NH1; h++) sp[h] += p[h];
    float2* plw = (float2*)pl[w][lane];
#pragma unroll
    for (int q = 0; q < 5; q++) plw[q] = float2{p[2 * q], p[2 * q + 1]};
    __builtin_amdgcn_wave_barrier();

    int j2 = 0;
    for (; j2 + 4 <= cnt; j2 += 4) {
      int sA = __shfl(msrc, j2),     sB = __shfl(msrc, j2 + 1);
      int sC = __shfl(msrc, j2 + 2), sD = __shfl(msrc, j2 + 3);
      const u32* ra = xrow + (size_t)sA * XW;
      const u32* rb = xrow + (size_t)sB * XW;
      const u32* rc = xrow + (size_t)sC * XW;
      const u32* rd = xrow + (size_t)sD * XW;
      u32 ua0 = ra[kp0], ua1 = ra[kp1], ua2 = ra[kp2];
      u32 ub0 = rb[kp0], ub1 = rb[kp1], ub2 = rb[kp2];
      u32 uc0 = rc[kp0], uc1 = rc[kp1], uc2 = rc[kp2];
      u32 ud0 = rd[kp0], ud1 = rd[kp1], ud2 = rd[kp2];
      const float* pA = pl[w][j2];
      const float* pB = pl[w][j2 + 1];
      const float* pC = pl[w][j2 + 2];
      const float* pD = pl[w][j2 + 3];
      float cA0 = pA[h0], cA1 = pA[h1i], cA2 = pA[h2i];
      float cB0 = pB[h0], cB1 = pB[h1i], cB2 = pB[h2i];
      float cC0 = pC[h0], cC1 = pC[h1i], cC2 = pC[h2i];
      float cD0 = pD[h0], cD1 = pD[h1i], cD2 = pD[h2i];
      float2 f;
      f = h2f(ua0); a0x = fmaf(cA0, f.x, a0x); a0y = fmaf(cA0, f.y, a0y);
      f = h2f(ua1); a1x = fmaf(cA1, f.x, a1x); a1y = fmaf(cA1, f.y, a1y);
      f = h2f(ua2); a2x = fmaf(cA2, f.x, a2x); a2y = fmaf(cA2, f.y, a2y);
      f = h2f(ub0); a0x = fmaf(cB0, f.x, a0x); a0y = fmaf(cB0, f.y, a0y);
      f = h2f(ub1); a1x = fmaf(cB1, f.x, a1x); a1y = fmaf(cB1, f.y, a1y);
      f = h2f(ub2); a2x = fmaf(cB2, f.x, a2x); a2y = fmaf(cB2, f.y, a2y);
      f = h2f(uc0); a0x = fmaf(cC0, f.x, a0x); a0y = fmaf(cC0, f.y, a0y);
      f = h2f(uc1); a1x = fmaf(cC1, f.x, a1x); a1y = fmaf(cC1, f.y, a1y);
      f = h2f(uc2); a2x = fmaf(cC2, f.x, a2x); a2y = fmaf(cC2, f.y, a2y);
      f = h2f(ud0); a0x = fmaf(cD0, f.x, a0x); a0y = fmaf(cD0, f.y, a0y);
      f = h2f(ud1); a1x = fmaf(cD1, f.x, a1x); a1y = fmaf(cD1, f.y, a1y);
      f = h2f(ud2); a2x = fmaf(cD2, f.x, a2x); a2y = fmaf(cD2, f.y, a2y);
    }
    for (; j2 < cnt; j2++) {
      int sA = __shfl(msrc, j2);
      const u32* ra = xrow + (size_t)sA * XW;
      u32 ua0 = ra[kp0], ua1 = ra[kp1], ua2 = ra[kp2];
      const float* pA = pl[w][j2];
      float cA0 = pA[h0], cA1 = pA[h1i], cA2 = pA[h2i];
      float2 f;
      f = h2f(ua0); a0x = fmaf(cA0, f.x, a0x); a0y = fmaf(cA0, f.y, a0y);
      f = h2f(ua1); a1x = fmaf(cA1, f.x, a1x); a1y = fmaf(cA1, f.y, a1y);
      f = h2f(ua2); a2x = fmaf(cA2, f.x, a2x); a2y = fmaf(cA2, f.y, a2y);
    }
    __builtin_amdgcn_wave_barrier();
  }

  // reduce per-lane partial sums -> softmax denominators
#pragma unroll
  for (int h = 0; h < NH1; h++) {
    float t = sp[h];
#pragma unroll
    for (int off = 32; off; off >>= 1) t += __shfl_xor(t, off);
    sp[h] = t;
  }
  float i0 = 1.f / (sp[h0] + 1e-16f);
  float i1 = 1.f / (sp[h1i] + 1e-16f);
  float i2 = 1.f / (sp[h2i] + 1e-16f);
  u32* orow = aggx2 + (size_t)node * (D1 / 2);
  orow[lane] = f2h2(a0x * i0, a0y * i0);
  orow[lane + 64] = f2h2(a1x * i1, a1y * i1);
  if (v2) orow[lane + 128] = f2h2(a2x * i2, a2y * i2);
}

// ---------------- mix1: hact[n,hc] = ELU( sum_k agg[n,h,k]*W1[k,hc] + b1[hc] ), K-padded to 384 ----------------
#define MIX_NPB 32
__global__ __launch_bounds__(384)
void k_mix1(const u32* __restrict__ aggx2, const u32* __restrict__ W1t2,
            const float* __restrict__ b1, __half* __restrict__ hact) {
  __shared__ u32 ag[MIX_NPB][D1 / 2 + 4];
  int t = threadIdx.x;
  int nb = blockIdx.x * MIX_NPB;
  int lim = min(MIX_NPB, N_NODES - nb);
  const u32* gsrc = aggx2 + (size_t)nb * (D1 / 2);
  for (int i = t; i < lim * (D1 / 2); i += 384) {
    int n = i / (D1 / 2), k = i - n * (D1 / 2);
    ag[n][k] = gsrc[i];
  }
  __syncthreads();
  if (t < D1) {
    int h = t / C1;
    u32 wreg[F_IN / 2];
#pragma unroll
    for (int kp = 0; kp < F_IN / 2; kp++) wreg[kp] = W1t2[t * (F_IN / 2) + kp];
    float bj = b1[t];
    for (int n = 0; n < lim; n++) {
      const u32* a = &ag[n][h * (F_IN / 2)];
      float acc2 = 0.f;
#pragma unroll
      for (int kp = 0; kp < F_IN / 2; kp++) acc2 = dot2acc(a[kp], wreg[kp], acc2);
      float val = acc2 + bj;
      val = val > 0.f ? val : __expf(val) - 1.f;   // ELU
      hact[(size_t)(nb + n) * HPAD + t] = __float2half(val);
    }
  } else {
    // zero-fill K padding [360,384)
    for (int n = 0; n < lim; n++)
      hact[(size_t)(nb + n) * HPAD + t] = __float2half(0.f);
  }
}

// ---------------- GEMM2 via MFMA + fused als2/ald2: h2 = hact @ W2  [N,128] ----------------
// v_mfma_f32_16x16x16f16: A lane l holds A[l&15][4*(l>>4)+j]; D: col=lane&15, row=4*(lane>>4)+r.
// Block = 4 waves x 16 rows = 64 rows; each wave does all 8 col-tiles over 24 k-chunks.
// Epilogue also computes als2/ald2 = h2 . a_{src,dst}2 via in-register row dots + 16-lane reduce.
__global__ __launch_bounds__(256)
void k_gemm2(const u32* __restrict__ hact32, const u32* __restrict__ W2f,
             const float* __restrict__ asrc2, const float* __restrict__ adst2,
             __half* __restrict__ h2h, float* __restrict__ als, float* __restrict__ ald) {
  int w = threadIdx.x >> 6, l = threadIdx.x & 63;
  int rowbase = blockIdx.x * 64 + w * 16;
  int m = l & 15, kb = l >> 4;
  int arow = rowbase + m;
  if (arow >= N_NODES) arow = N_NODES - 1;     // clamp loads; stores guarded
  const u32* ap = hact32 + (size_t)arow * KW + kb * 2;
  const uint2* bp = (const uint2*)W2f;
  int col0 = l & 15;
  float asv[8], adv[8];
#pragma unroll
  for (int t = 0; t < 8; t++) { asv[t] = asrc2[t * 16 + col0]; adv[t] = adst2[t * 16 + col0]; }
  f32x4 acc[8];
#pragma unroll
  for (int t = 0; t < 8; t++) acc[t] = (f32x4){0.f, 0.f, 0.f, 0.f};
#pragma unroll 4
  for (int kc = 0; kc < KCH; kc++) {
    uint2 aw = *(const uint2*)(ap + kc * 8);
    f16x4 af = __builtin_bit_cast(f16x4, aw);
#pragma unroll
    for (int t = 0; t < 8; t++) {
      uint2 bw = bp[(kc * 8 + t) * 64 + l];
      acc[t] = __builtin_amdgcn_mfma_f32_16x16x16f16(af, __builtin_bit_cast(f16x4, bw),
                                                     acc[t], 0, 0, 0);
    }
  }
  int orow0 = rowbase + (l >> 4) * 4;
#pragma unroll
  for (int t = 0; t < 8; t++) {
#pragma unroll
    for (int r = 0; r < 4; r++) {
      int row = orow0 + r;
      if (row < N_NODES)
        h2h[(size_t)row * D2 + t * 16 + col0] = __float2half(acc[t][r]);
    }
  }
  // fused attention scalars: reduce each row's dot over the 16-lane column group
#pragma unroll
  for (int r = 0; r < 4; r++) {
    float sa = 0.f, sd = 0.f;
#pragma unroll
    for (int t = 0; t < 8; t++) {
      sa = fmaf(acc[t][r], asv[t], sa);
      sd = fmaf(acc[t][r], adv[t], sd);
    }
#pragma unroll
    for (int off = 1; off < 16; off <<= 1) {
      sa += __shfl_xor(sa, off);
      sd += __shfl_xor(sd, off);
    }
    int row = orow0 + r;
    if (col0 == 0 && row < N_NODES) { als[row] = sa; ald[row] = sd; }
  }
}

// ---------------- layer-2 fused softmax + aggregate + ReLU + max-pool ----------------
// Uniform-lane shuffles -> scalar-base coalesced row gathers; 4-edge unroll for MLP.
__global__ __launch_bounds__(256)
void k_agg2(const __half* __restrict__ h2h, const float* __restrict__ als,
            const float* __restrict__ ald, const int* __restrict__ row_ptr,
            const int* __restrict__ csr_src, const float* __restrict__ b2,
            const int* __restrict__ batch, u32* __restrict__ pool) {
  int w = threadIdx.x >> 6, lane = threadIdx.x & 63;
  int node = blockIdx.x * 4 + w;
  int beg = row_ptr[node], end = row_ptr[node + 1];
  float aldn = ald[node];
  float ax = 0.f, ay = 0.f, ssum = 0.f;
  for (int base = beg; base < end; base += 64) {
    int cnt = min(64, end - base);
    int msrc = 0; float p = 0.f;
    if (lane < cnt) {
      msrc = csr_src[base + lane];
      float vv = als[msrc] + aldn;
      vv = vv > 0.f ? vv : 0.2f * vv;
      p = __expf(vv);
    }
    ssum += p;   // per-lane partial; reduced at end
    int j2 = 0;
    for (; j2 + 4 <= cnt; j2 += 4) {
      int sA = __shfl(msrc, j2),     sB = __shfl(msrc, j2 + 1);
      int sC = __shfl(msrc, j2 + 2), sD = __shfl(msrc, j2 + 3);
      float cA = __shfl(p, j2),      cB = __shfl(p, j2 + 1);
      float cC = __shfl(p, j2 + 2),  cD = __shfl(p, j2 + 3);
      u32 ua = ((const u32*)(h2h + (size_t)sA * D2))[lane];
      u32 ub = ((const u32*)(h2h + (size_t)sB * D2))[lane];
      u32 uc = ((const u32*)(h2h + (size_t)sC * D2))[lane];
      u32 ud = ((const u32*)(h2h + (size_t)sD * D2))[lane];
      float2 f;
      f = h2f(ua); ax = fmaf(cA, f.x, ax); ay = fmaf(cA, f.y, ay);
      f = h2f(ub); ax = fmaf(cB, f.x, ax); ay = fmaf(cB, f.y, ay);
      f = h2f(uc); ax = fmaf(cC, f.x, ax); ay = fmaf(cC, f.y, ay);
      f = h2f(ud); ax = fmaf(cD, f.x, ax); ay = fmaf(cD, f.y, ay);
    }
    for (; j2 < cnt; j2++) {
      int sA = __shfl(msrc, j2);
      float cA = __shfl(p, j2);
      u32 ua = ((const u32*)(h2h + (size_t)sA * D2))[lane];
      float2 f = h2f(ua); ax = fmaf(cA, f.x, ax); ay = fmaf(cA, f.y, ay);
    }
  }
  float t2 = ssum;
#pragma unroll
  for (int off = 32; off; off >>= 1) t2 += __shfl_xor(t2, off);
  float inv = 1.f / (t2 + 1e-16f);
  float2 bv = ((const float2*)b2)[lane];
  float vx = fmaxf(ax * inv + bv.x, 0.f);
  float vy = fmaxf(ay * inv + bv.y, 0.f);
  int g = batch[node];
  // unconditional atomicMax: pre-check load of cross-XCD-hot lines REGRESSED 2x (R12)
  atomicMax(&pool[(size_t)g * D2 + 2 * lane],     __float_as_uint(vx));
  atomicMax(&pool[(size_t)g * D2 + 2 * lane + 1], __float_as_uint(vy));
}

// ---------------- final FC + relu ----------------
__global__ void k_final(const float* __restrict__ pool, const float* __restrict__ fcw,
                        const float* __restrict__ fcb, float* __restrict__ out) {
  __shared__ float ps[D2];
  int g = blockIdx.x, j = threadIdx.x;
  ps[j] = pool[g * D2 + j];
  __syncthreads();
  float acc = 0.f;
  for (int c = 0; c < D2; c++) acc = fmaf(ps[c], fcw[c * D2 + j], acc);
  acc += fcb[j];
  out[g * D2 + j] = acc > 0.f ? acc : 0.f;
}

extern "C" void kernel_launch(void* const* d_in, const int* in_sizes, int n_in,
                              void* d_out, int out_size, void* d_ws, size_t ws_size,
                              hipStream_t stream) {
  const float* x     = (const float*)d_in[0];
  const int*   ei    = (const int*)d_in[1];
  const int*   batch = (const int*)d_in[2];
  const float* W1    = (const float*)d_in[3];
  const float* asrc1 = (const float*)d_in[4];
  const float* adst1 = (const float*)d_in[5];
  const float* b1    = (const float*)d_in[6];
  const float* W2    = (const float*)d_in[7];
  const float* asrc2 = (const float*)d_in[8];
  const float* adst2 = (const float*)d_in[9];
  const float* b2    = (const float*)d_in[10];
  const float* fcw   = (const float*)d_in[11];
  const float* fcb   = (const float*)d_in[12];
  float* out = (float*)d_out;

  char* w = (char*)d_ws;
  size_t off = 0;
  auto alloc = [&](size_t bytes) -> char* {
    char* p = w + off;
    off = (off + bytes + 255) & ~(size_t)255;
    return p;
  };
  int* counts    = (int*)alloc((size_t)N_NODES * 4);
  int* row_ptr   = (int*)alloc((size_t)(N_NODES + 1) * 4);
  int* nxt       = (int*)alloc((size_t)N_NODES * 4);
  int* csr_src   = (int*)alloc((size_t)E_TOT * 4);
  int* partial   = (int*)alloc(NCHUNK * 4);
  int* chunk_off = (int*)alloc(NCHUNK * 4);
  float* als1    = (float*)alloc((size_t)N_NODES * NH1 * 4);
  float* ald1    = (float*)alloc((size_t)N_NODES * NH1 * 4);
  float* als2    = (float*)alloc((size_t)N_NODES * 4);
  float* ald2    = (float*)alloc((size_t)N_NODES * 4);
  u32*   pool    = (u32*)alloc((size_t)N_GRAPHS * D2 * 4);
  float* w_als   = (float*)alloc((size_t)D1 * 4);
  float* w_ald   = (float*)alloc((size_t)D1 * 4);
  u32*   W1t2    = (u32*)alloc((size_t)D1 * (F_IN / 2) * 4);
  u32*   W2f     = (u32*)alloc((size_t)W2FW * 4);
  u32*   xh2     = (u32*)alloc((size_t)N_NODES * XW * 4);
  u32*   aggx2   = (u32*)alloc((size_t)N_NODES * (D1 / 2) * 4);
  __half* hacth  = (__half*)alloc((size_t)N_NODES * HPAD * 2);
  // aggx2 (36 MB) is dead after k_mix1 -> alias h2h (12.8 MB) into its region.
  // Keeps peak workspace ~86.6 MB, below the 97 MB proven safe in round 5.
  __half* h2h = (__half*)aggx2;

  k_init<<<dim3(196), dim3(256), 0, stream>>>(counts, pool);
  k_hist<<<dim3((E_TOT + 255) / 256), dim3(256), 0, stream>>>(ei, counts);
  k_scan1<<<dim3(NCHUNK), dim3(256), 0, stream>>>(counts, partial);
  k_scan2<<<dim3(1), dim3(64), 0, stream>>>(partial, chunk_off, row_ptr);
  k_scan3<<<dim3(NCHUNK), dim3(SCHUNK), 0, stream>>>(counts, chunk_off, row_ptr, nxt);
  k_scatter<<<dim3((E_TOT + 255) / 256), dim3(256), 0, stream>>>(ei, nxt, csr_src);
  k_prep<<<dim3(123), dim3(256), 0, stream>>>(W1, asrc1, adst1, W2, w_als, w_ald, W1t2, W2f);

  k_als1<<<dim3((N_NODES + 63) / 64), dim3(256), 0, stream>>>(x, w_als, w_ald, als1, ald1, xh2);
  k_agg1<<<dim3(N_NODES / 4), dim3(256), 0, stream>>>(xh2, als1, ald1, row_ptr, csr_src, aggx2);
  k_mix1<<<dim3((N_NODES + MIX_NPB - 1) / MIX_NPB), dim3(384), 0, stream>>>(aggx2, W1t2, b1, hacth);

  k_gemm2<<<dim3((N_NODES + 63) / 64), dim3(256), 0, stream>>>((const u32*)hacth, W2f,
                                                               asrc2, adst2, h2h, als2, ald2);
  k_agg2<<<dim3(N_NODES / 4), dim3(256), 0, stream>>>(h2h, als2, ald2, row_ptr, csr_src,
                                                      b2, batch, pool);

  k_final<<<dim3(N_GRAPHS), dim3(D2), 0, stream>>>((const float*)pool, fcw, fcb, out);

  (void)in_sizes; (void)n_in; (void)out_size; (void)ws_size;
}